// Round 14
// baseline (295.802 us; speedup 1.0000x reference)
//
#include <hip/hip_runtime.h>
#include <hip/hip_bf16.h>

constexpr int Bb = 2, Nn = 2048, Ff = 768, Hh = 8, Oo = 256;

typedef __attribute__((ext_vector_type(8)))  short   short8;
typedef __attribute__((ext_vector_type(16))) float   f32x16;
typedef __attribute__((ext_vector_type(4)))  unsigned short ushort4_t;

__device__ inline unsigned short f2bf(float f) {
    unsigned u = __float_as_uint(f);
    u = (u + 0x7FFFu + ((u >> 16) & 1u)) >> 16;   // RNE
    return (unsigned short)u;
}

// ---------------- adjacency bitmask ----------------
__global__ __launch_bounds__(256) void adjbits_kernel(
        const float* __restrict__ adj, unsigned long long* __restrict__ bits) {
    size_t gid = (size_t)blockIdx.x * 256 + threadIdx.x;
    float v = adj[gid];
    unsigned long long m = __ballot(v > 0.f);
    if ((threadIdx.x & 63) == 0) bits[gid >> 6] = m;
}

// ---------------- f32 -> bf16 flat cast ----------------
__global__ __launch_bounds__(256) void cast_bf_kernel(
        const float* __restrict__ in, unsigned short* __restrict__ out) {
    size_t i = (size_t)blockIdx.x * 256 + threadIdx.x;
    float4 v = ((const float4*)in)[i];
    ushort4_t o;
    o.x = f2bf(v.x); o.y = f2bf(v.y); o.z = f2bf(v.z); o.w = f2bf(v.w);
    ((ushort4_t*)out)[i] = o;
}

// ======== B-fragment layout: frag id = nt32*(K/16)+kt, 1 KB each ========
__global__ __launch_bounds__(256) void wfrag_kn_kernel(
        const float* __restrict__ W, unsigned short* __restrict__ out,
        int K, int N, long long sW, long long sO) {
    W   += (size_t)blockIdx.y * sW;
    out += (size_t)blockIdx.y * sO;
    int t = threadIdx.x;
    int f = blockIdx.x * 4 + (t >> 6);
    int slot = t & 63, kh = slot >> 5, lm = slot & 31;
    int nfk = K >> 4;
    int nt = f / nfk, kt = f - nt * nfk;
    const float* wp = W + (size_t)(kt * 16 + kh * 8) * N + nt * 32 + lm;
    ushort4_t o0, o1;
    o0.x = f2bf(wp[0]);             o0.y = f2bf(wp[(size_t)N]);
    o0.z = f2bf(wp[2 * (size_t)N]); o0.w = f2bf(wp[3 * (size_t)N]);
    o1.x = f2bf(wp[4 * (size_t)N]); o1.y = f2bf(wp[5 * (size_t)N]);
    o1.z = f2bf(wp[6 * (size_t)N]); o1.w = f2bf(wp[7 * (size_t)N]);
    unsigned short* op = out + (size_t)f * 512 + slot * 8;
    *(ushort4_t*)op = o0;
    *(ushort4_t*)(op + 4) = o1;
}

__global__ __launch_bounds__(256) void wfrag_nk_kernel(
        const float* __restrict__ W, unsigned short* __restrict__ out, int K) {
    int t = threadIdx.x;
    int f = blockIdx.x * 4 + (t >> 6);
    int slot = t & 63, kh = slot >> 5, lm = slot & 31;
    int nfk = K >> 4;
    int nt = f / nfk, kt = f - nt * nfk;
    const float* wp = W + (size_t)(nt * 32 + lm) * K + kt * 16 + kh * 8;
    float4 a = *(const float4*)wp, b = *(const float4*)(wp + 4);
    ushort4_t o0, o1;
    o0.x = f2bf(a.x); o0.y = f2bf(a.y); o0.z = f2bf(a.z); o0.w = f2bf(a.w);
    o1.x = f2bf(b.x); o1.y = f2bf(b.y); o1.z = f2bf(b.z); o1.w = f2bf(b.w);
    unsigned short* op = out + (size_t)f * 512 + slot * 8;
    *(ushort4_t*)op = o0;
    *(ushort4_t*)(op + 4) = o1;
}

// ---------------- MFMA GEMM, BK=64, optional fused scores epilogue ----------------
__global__ __launch_bounds__(256) void gemm_bf_kernel(
        const unsigned short* __restrict__ A, int K, long long sA, int bAshift,
        const unsigned short* __restrict__ BF, long long sB, int bmask,
        float* __restrict__ C, long long sC,
        unsigned short* __restrict__ CF, long long sCF, int Mtot,
        const float* __restrict__ bias, int mode,
        const float* __restrict__ aall, int amask,
        float* __restrict__ E1p, float* __restrict__ E1n, float2* __restrict__ E2pn) {
    int z = blockIdx.z;
    A  += (size_t)(z >> bAshift) * sA;
    BF += (size_t)(z & bmask) * sB;
    if (C) C += (size_t)z * sC;
    if (CF) CF += (size_t)z * sCF;
    int m0 = blockIdx.x * 64;
    int t = threadIdx.x;
    int wv = t >> 6, lane = t & 63;
    int lm = lane & 31, kh = lane >> 5;
    int nfk = K >> 4;
    __shared__ __align__(16) unsigned short As[64][72];
    f32x16 acc[2][2] = {};
    int sr = t >> 2, sc2 = (t & 3) * 16;
    const unsigned short* ag  = A + (size_t)(m0 + sr) * K + sc2;
    const unsigned short* bg0 = BF + (size_t)(wv * 2) * nfk * 512;
    const unsigned short* bg1 = bg0 + (size_t)nfk * 512;
    for (int k0 = 0; k0 < K; k0 += 64) {
        *(short8*)&As[sr][sc2]     = *(const short8*)(ag + k0);
        *(short8*)&As[sr][sc2 + 8] = *(const short8*)(ag + k0 + 8);
        int kt0 = k0 >> 4;
        __syncthreads();
#pragma unroll
        for (int s = 0; s < 4; ++s) {
            short8 a0 = *(const short8*)&As[lm][s * 16 + kh * 8];
            short8 a1 = *(const short8*)&As[32 + lm][s * 16 + kh * 8];
            short8 b0 = *(const short8*)(bg0 + (size_t)(kt0 + s) * 512 + lane * 8);
            short8 b1 = *(const short8*)(bg1 + (size_t)(kt0 + s) * 512 + lane * 8);
            acc[0][0] = __builtin_amdgcn_mfma_f32_32x32x16_bf16(a0, b0, acc[0][0], 0, 0, 0);
            acc[0][1] = __builtin_amdgcn_mfma_f32_32x32x16_bf16(a0, b1, acc[0][1], 0, 0, 0);
            acc[1][0] = __builtin_amdgcn_mfma_f32_32x32x16_bf16(a1, b0, acc[1][0], 0, 0, 0);
            acc[1][1] = __builtin_amdgcn_mfma_f32_32x32x16_bf16(a1, b1, acc[1][1], 0, 0, 0);
        }
        __syncthreads();
    }
#pragma unroll
    for (int mt = 0; mt < 2; ++mt)
#pragma unroll
        for (int nt = 0; nt < 2; ++nt) {
            int colg = wv * 64 + nt * 32 + lm;
            float bv = (mode == 2) ? bias[colg] : 0.f;
            if (C) {
#pragma unroll
                for (int reg = 0; reg < 16; ++reg) {
                    int rl = mt * 32 + 4 * kh + (reg & 3) + 8 * (reg >> 2);
                    float v = acc[mt][nt][reg];
                    if (mode == 2) { v += bv; v = fmaxf(v, 0.f); }
                    C[(size_t)(m0 + rl) * 256 + colg] = v;
                }
            }
            if (mode == 1) {
#pragma unroll
                for (int q = 0; q < 4; ++q) {
                    int kt = m0 / 16 + mt * 2 + (q >> 1);
                    size_t fi = ((size_t)(colg >> 5) * (Mtot / 16) + kt) * 512 +
                                ((q & 1) * 32 + (colg & 31)) * 8 + kh * 4;
                    ushort4_t pk;
                    pk.x = f2bf(acc[mt][nt][q * 4 + 0]);
                    pk.y = f2bf(acc[mt][nt][q * 4 + 1]);
                    pk.z = f2bf(acc[mt][nt][q * 4 + 2]);
                    pk.w = f2bf(acc[mt][nt][q * 4 + 3]);
                    *(ushort4_t*)(CF + fi) = pk;
                }
            }
        }
    if (aall) {
        const float* av = aall + (size_t)(z & amask) * 512;
        float a1v0 = av[wv * 64 + lm],       a1v1 = av[wv * 64 + 32 + lm];
        float a2v0 = av[256 + wv * 64 + lm], a2v1 = av[256 + wv * 64 + 32 + lm];
        float* sbuf = (float*)As;
#pragma unroll
        for (int mt = 0; mt < 2; ++mt)
#pragma unroll
            for (int reg = 0; reg < 16; ++reg) {
                int rl = mt * 32 + 4 * kh + (reg & 3) + 8 * (reg >> 2);
                float v1 = acc[mt][0][reg] * a1v0 + acc[mt][1][reg] * a1v1;
                float v2 = acc[mt][0][reg] * a2v0 + acc[mt][1][reg] * a2v1;
#pragma unroll
                for (int m = 1; m <= 16; m <<= 1) {
                    v1 += __shfl_xor(v1, m, 64);
                    v2 += __shfl_xor(v2, m, 64);
                }
                if (lm == 0) { sbuf[rl * 8 + wv] = v1; sbuf[rl * 8 + 4 + wv] = v2; }
            }
        __syncthreads();
        if (t < 64) {
            float s1 = sbuf[t * 8] + sbuf[t * 8 + 1] + sbuf[t * 8 + 2] + sbuf[t * 8 + 3];
            float s2 = sbuf[t * 8 + 4] + sbuf[t * 8 + 5] + sbuf[t * 8 + 6] + sbuf[t * 8 + 7];
            size_t ei = (size_t)z * Nn + m0 + t;
            E1p[ei] = __expf(s1);
            E1n[ei] = __expf(0.2f * s1);
            E2pn[ei] = make_float2(__expf(s2), __expf(0.2f * s2));
        }
    }
}

// ---------------- dual MFMA GEMM, BK=64: x1 @ [WoF ; WlF]; ng0 + fused sh scores ----------------
__global__ __launch_bounds__(256) void gemm_dual_kernel(
        const unsigned short* __restrict__ A, int K, long long sA,
        const unsigned short* __restrict__ BF,
        unsigned short* __restrict__ h2f, float* __restrict__ lin,
        const float* __restrict__ a_out,
        float* __restrict__ E1p, float* __restrict__ E1n, float2* __restrict__ E2pn) {
    int b = blockIdx.z, ng = blockIdx.y;
    A += (size_t)b * sA;
    int nfk = K >> 4;
    BF += (size_t)ng * 8 * nfk * 512;
    int m0 = blockIdx.x * 64;
    int t = threadIdx.x;
    int wv = t >> 6, lane = t & 63;
    int lm = lane & 31, kh = lane >> 5;
    __shared__ __align__(16) unsigned short As[64][72];
    f32x16 acc[2][2] = {};
    int sr = t >> 2, sc2 = (t & 3) * 16;
    const unsigned short* ag  = A + (size_t)(m0 + sr) * K + sc2;
    const unsigned short* bg0 = BF + (size_t)(wv * 2) * nfk * 512;
    const unsigned short* bg1 = bg0 + (size_t)nfk * 512;
    for (int k0 = 0; k0 < K; k0 += 64) {
        *(short8*)&As[sr][sc2]     = *(const short8*)(ag + k0);
        *(short8*)&As[sr][sc2 + 8] = *(const short8*)(ag + k0 + 8);
        int kt0 = k0 >> 4;
        __syncthreads();
#pragma unroll
        for (int s = 0; s < 4; ++s) {
            short8 a0 = *(const short8*)&As[lm][s * 16 + kh * 8];
            short8 a1 = *(const short8*)&As[32 + lm][s * 16 + kh * 8];
            short8 b0 = *(const short8*)(bg0 + (size_t)(kt0 + s) * 512 + lane * 8);
            short8 b1 = *(const short8*)(bg1 + (size_t)(kt0 + s) * 512 + lane * 8);
            acc[0][0] = __builtin_amdgcn_mfma_f32_32x32x16_bf16(a0, b0, acc[0][0], 0, 0, 0);
            acc[0][1] = __builtin_amdgcn_mfma_f32_32x32x16_bf16(a0, b1, acc[0][1], 0, 0, 0);
            acc[1][0] = __builtin_amdgcn_mfma_f32_32x32x16_bf16(a1, b0, acc[1][0], 0, 0, 0);
            acc[1][1] = __builtin_amdgcn_mfma_f32_32x32x16_bf16(a1, b1, acc[1][1], 0, 0, 0);
        }
        __syncthreads();
    }
    if (ng == 1) {
        float* C = lin + (size_t)b * Nn * 256;
#pragma unroll
        for (int mt = 0; mt < 2; ++mt)
#pragma unroll
            for (int nt = 0; nt < 2; ++nt) {
                int colg = wv * 64 + nt * 32 + lm;
#pragma unroll
                for (int reg = 0; reg < 16; ++reg) {
                    int rl = mt * 32 + 4 * kh + (reg & 3) + 8 * (reg >> 2);
                    C[(size_t)(m0 + rl) * 256 + colg] = acc[mt][nt][reg];
                }
            }
    } else {
        unsigned short* CF = h2f + (size_t)b * 524288;
#pragma unroll
        for (int mt = 0; mt < 2; ++mt)
#pragma unroll
            for (int nt = 0; nt < 2; ++nt) {
                int colg = wv * 64 + nt * 32 + lm;
#pragma unroll
                for (int q = 0; q < 4; ++q) {
                    int kt = m0 / 16 + mt * 2 + (q >> 1);
                    size_t fi = ((size_t)(colg >> 5) * 128 + kt) * 512 +
                                ((q & 1) * 32 + (colg & 31)) * 8 + kh * 4;
                    ushort4_t pk;
                    pk.x = f2bf(acc[mt][nt][q * 4 + 0]);
                    pk.y = f2bf(acc[mt][nt][q * 4 + 1]);
                    pk.z = f2bf(acc[mt][nt][q * 4 + 2]);
                    pk.w = f2bf(acc[mt][nt][q * 4 + 3]);
                    *(ushort4_t*)(CF + fi) = pk;
                }
            }
        float a1v0 = a_out[wv * 64 + lm],       a1v1 = a_out[wv * 64 + 32 + lm];
        float a2v0 = a_out[256 + wv * 64 + lm], a2v1 = a_out[256 + wv * 64 + 32 + lm];
        float* sbuf = (float*)As;
#pragma unroll
        for (int mt = 0; mt < 2; ++mt)
#pragma unroll
            for (int reg = 0; reg < 16; ++reg) {
                int rl = mt * 32 + 4 * kh + (reg & 3) + 8 * (reg >> 2);
                float v1 = acc[mt][0][reg] * a1v0 + acc[mt][1][reg] * a1v1;
                float v2 = acc[mt][0][reg] * a2v0 + acc[mt][1][reg] * a2v1;
#pragma unroll
                for (int m = 1; m <= 16; m <<= 1) {
                    v1 += __shfl_xor(v1, m, 64);
                    v2 += __shfl_xor(v2, m, 64);
                }
                if (lm == 0) { sbuf[rl * 8 + wv] = v1; sbuf[rl * 8 + 4 + wv] = v2; }
            }
        __syncthreads();
        if (t < 64) {
            float s1 = sbuf[t * 8] + sbuf[t * 8 + 1] + sbuf[t * 8 + 2] + sbuf[t * 8 + 3];
            float s2 = sbuf[t * 8 + 4] + sbuf[t * 8 + 5] + sbuf[t * 8 + 6] + sbuf[t * 8 + 7];
            size_t ei = (size_t)b * Nn + m0 + t;
            E1p[ei] = __expf(s1);
            E1n[ei] = __expf(0.2f * s1);
            E2pn[ei] = make_float2(__expf(s2), __expf(0.2f * s2));
        }
    }
}

// ---------------- attention v7: 3-stage ps ring, 2-chunk-ahead prefetch ----------------
// Per period c: mfma(ps[c%3], B[c&1]) -> computeP(c+2 -> ps[(c+2)%3]) -> loadB(c+2 -> B[c&1])
// -> one barrier. MFMA consumes P written 2 barriers ago (no freshness wait); loads have
// ~1 full period in flight. Slots distinct mod 3 per period; B WAR ordered after mfma.
template<int JLEN, int MODE, int SWAPXY>
__global__ __launch_bounds__(256, 2) void attn_v7_kernel(
        const unsigned short* __restrict__ hfrag,
        const unsigned* __restrict__ bits,
        const float* __restrict__ E1p, const float* __restrict__ E1n,
        const float2* __restrict__ E2pn,
        unsigned short* __restrict__ outbf, int ldo,
        float* __restrict__ pacc, float* __restrict__ plsum,
        int hshift) {
    constexpr int W = JLEN / 32, NC = JLEN / 64, ABS = W + 1;
    int it = SWAPXY ? blockIdx.y : blockIdx.x;
    int bh = SWAPXY ? blockIdx.x : blockIdx.y;
    int js = blockIdx.z;
    int b = bh >> hshift, hd = bh & ((1 << hshift) - 1);
    int i0 = it * 64, jbase = js * JLEN;
    int kt0 = js * (JLEN / 16);
    int t = threadIdx.x, lane = t & 63;
    int wv = t >> 6, lm = lane & 31, kh = lane >> 5;
    int ti = lane, jq = wv;

    __shared__ unsigned ab[64 * ABS];
    __shared__ __align__(16) unsigned short ps[3][64][64];   // 3-stage ring
    __shared__ float lred[64][5];
    __shared__ float linv[64];

    const unsigned* bb = bits + ((size_t)b * Nn + i0) * 64 + (jbase >> 5);
    for (int k = t; k < 64 * W; k += 256) {
        int r = k / W, w0 = k - r * W;
        ab[r * ABS + w0] = bb[(size_t)r * 64 + w0];
    }
    __syncthreads();   // ab[] must be visible before computeP

    float e1p = E1p[(size_t)bh * Nn + i0 + ti];
    float e1n = E1n[(size_t)bh * Nn + i0 + ti];
    const float4* e2base = (const float4*)(E2pn + (size_t)bh * Nn + jbase);

    const unsigned short* bg0 = hfrag + (size_t)bh * 524288 + (size_t)(wv * 2) * 128 * 512;
    const unsigned short* bg1 = bg0 + 128 * 512;

    f32x16 acc[2][2] = {};
    float lp0 = 0.f, lp1 = 0.f;
    short8 B0[8], B1[8];

    auto loadB = [&](int c, short8* B) {
#pragma unroll
        for (int s = 0; s < 4; ++s) {
            int kt = kt0 + c * 4 + s;
            B[2 * s]     = *(const short8*)(bg0 + (size_t)kt * 512 + lane * 8);
            B[2 * s + 1] = *(const short8*)(bg1 + (size_t)kt * 512 + lane * 8);
        }
    };
    auto computeP = [&](int c, int buf) {
        int cj = c * 64;
        unsigned word = ab[ti * ABS + ((cj >> 5) + (jq >> 1))];
        unsigned field = word >> ((jq & 1) * 16);
        const float4* ep = e2base + ((cj + jq * 16) >> 1);
        unsigned pk[8];
#pragma unroll
        for (int u = 0; u < 8; ++u) {
            float4 q = ep[u];
            float p0 = fmaxf(e1p * q.x, e1n * q.y);   // select==max (exact)
            p0 = ((field >> (2 * u)) & 1u) ? p0 : 0.f;
            float p1 = fmaxf(e1p * q.z, e1n * q.w);
            p1 = ((field >> (2 * u + 1)) & 1u) ? p1 : 0.f;
            if (u & 1) lp1 += p0 + p1; else lp0 += p0 + p1;
            __hip_bfloat162 hv = __float22bfloat162_rn(make_float2(p0, p1));
            pk[u] = *(unsigned*)&hv;
        }
        unsigned sw = ti & 7;
        uint4 v0; v0.x = pk[0]; v0.y = pk[1]; v0.z = pk[2]; v0.w = pk[3];
        uint4 v1; v1.x = pk[4]; v1.y = pk[5]; v1.z = pk[6]; v1.w = pk[7];
        *(uint4*)&ps[buf][ti][((2 * jq) ^ sw) * 8]     = v0;
        *(uint4*)&ps[buf][ti][((2 * jq + 1) ^ sw) * 8] = v1;
    };
    auto mfmaStep = [&](int buf, short8* B) {
        unsigned sw = lm & 7;
#pragma unroll
        for (int s = 0; s < 4; ++s) {
            short8 a0 = *(const short8*)&ps[buf][lm][((2 * s + kh) ^ sw) * 8];
            short8 a1 = *(const short8*)&ps[buf][32 + lm][((2 * s + kh) ^ sw) * 8];
            acc[0][0] = __builtin_amdgcn_mfma_f32_32x32x16_bf16(a0, B[2 * s],     acc[0][0], 0, 0, 0);
            acc[0][1] = __builtin_amdgcn_mfma_f32_32x32x16_bf16(a0, B[2 * s + 1], acc[0][1], 0, 0, 0);
            acc[1][0] = __builtin_amdgcn_mfma_f32_32x32x16_bf16(a1, B[2 * s],     acc[1][0], 0, 0, 0);
            acc[1][1] = __builtin_amdgcn_mfma_f32_32x32x16_bf16(a1, B[2 * s + 1], acc[1][1], 0, 0, 0);
        }
    };

    // prologue: P(0),P(1) and B(0),B(1) in flight
    computeP(0, 0);
    computeP(1, 1);
    loadB(0, B0);
    loadB(1, B1);
    __syncthreads();
    for (int c = 0; c < NC; ++c) {
        short8* Bc = (c & 1) ? B1 : B0;
        mfmaStep(c % 3, Bc);                 // consumes P written 2 barriers ago
        if (c + 2 < NC) {
            computeP(c + 2, (c + 2) % 3);    // slot last read at period c-1 (pre-barrier)
            loadB(c + 2, Bc);                // WAR on Bc: after mfma issue
        }
        __syncthreads();
    }

    lred[ti][jq] = lp0 + lp1;
    __syncthreads();
    if (MODE == 0) {
        if (t < 64) linv[t] = 1.f / (lred[t][0] + lred[t][1] + lred[t][2] + lred[t][3]);
        __syncthreads();
#pragma unroll
        for (int mt = 0; mt < 2; ++mt)
#pragma unroll
            for (int nt = 0; nt < 2; ++nt) {
                int o = wv * 64 + nt * 32 + lm;
#pragma unroll
                for (int reg = 0; reg < 16; ++reg) {
                    int rl = mt * 32 + 4 * kh + (reg & 3) + 8 * (reg >> 2);
                    float v = acc[mt][nt][reg] * linv[rl];
                    v = v > 0.f ? v : expm1f(v);   // elu (layer 1)
                    outbf[((size_t)b * Nn + i0 + rl) * ldo + (size_t)hd * Oo + o] = f2bf(v);
                }
            }
    } else {
        if (t < 64)
            plsum[((size_t)js * Bb + b) * Nn + i0 + t] =
                lred[t][0] + lred[t][1] + lred[t][2] + lred[t][3];
        float* pa = pacc + (((size_t)js * Bb + b) * Nn) * 256;
#pragma unroll
        for (int mt = 0; mt < 2; ++mt)
#pragma unroll
            for (int nt = 0; nt < 2; ++nt) {
                int o = wv * 64 + nt * 32 + lm;
#pragma unroll
                for (int reg = 0; reg < 16; ++reg) {
                    int rl = mt * 32 + 4 * kh + (reg & 3) + 8 * (reg >> 2);
                    pa[(size_t)(i0 + rl) * 256 + o] = acc[mt][nt][reg];
                }
            }
    }
}

// ---------------- combine 8 partials: x2 = Σacc/Σl + lin + b ----------------
__global__ __launch_bounds__(256) void combine8_kernel(
        const float* __restrict__ pacc, const float* __restrict__ plsum,
        const float* __restrict__ lin, const float* __restrict__ bias,
        unsigned short* __restrict__ out) {
    int gid = blockIdx.x * 256 + threadIdx.x;
    int row = gid >> 6;
    int o4 = gid & 63;
    size_t ps4 = (size_t)Bb * Nn * 64;
    const float4* p = (const float4*)pacc + (size_t)row * 64 + o4;
    float4 s = p[0];
#pragma unroll
    for (int k = 1; k < 8; ++k) {
        float4 q = p[k * ps4];
        s.x += q.x; s.y += q.y; s.z += q.z; s.w += q.w;
    }
    int BN = Bb * Nn;
    float lsum = 0.f;
#pragma unroll
    for (int k = 0; k < 8; ++k) lsum += plsum[row + k * BN];
    float li = 1.f / lsum;
    float4 lv = ((const float4*)lin)[(size_t)row * 64 + o4];
    float4 bv = ((const float4*)bias)[o4];
    float4 v;
    v.x = s.x * li + lv.x + bv.x; v.y = s.y * li + lv.y + bv.y;
    v.z = s.z * li + lv.z + bv.z; v.w = s.w * li + lv.w + bv.w;
    __hip_bfloat162 h0 = __float22bfloat162_rn(make_float2(v.x, v.y));
    __hip_bfloat162 h1 = __float22bfloat162_rn(make_float2(v.z, v.w));
    uint2 st; st.x = *(unsigned*)&h0; st.y = *(unsigned*)&h1;
    *(uint2*)(out + (size_t)gid * 4) = st;
}

extern "C" void kernel_launch(void* const* d_in, const int* in_sizes, int n_in,
                              void* d_out, int out_size, void* d_ws, size_t ws_size,
                              hipStream_t stream) {
    const float* x       = (const float*)d_in[0];
    const float* adj     = (const float*)d_in[1];
    const float* W_heads = (const float*)d_in[3];
    const float* a_heads = (const float*)d_in[4];
    const float* W_out   = (const float*)d_in[5];
    const float* a_out   = (const float*)d_in[6];
    const float* W_lin   = (const float*)d_in[7];
    const float* b_lin   = (const float*)d_in[8];
    const float* W_ln    = (const float*)d_in[9];
    const float* b_ln    = (const float*)d_in[10];

    char* w = (char*)d_ws;
    float* pacc     = (float*)(w);                    // 8x4 MB (sh partials)
    float* lin      = (float*)(w + 33554432);
    float* E1p_mh   = (float*)(w + 41943040);
    float* E1n_mh   = (float*)(w + 42074112);
    float2* E2pn_mh = (float2*)(w + 42205184);
    float* E1p_sh   = (float*)(w + 42467328);
    float* E1n_sh   = (float*)(w + 42483712);
    float2* E2pn_sh = (float2*)(w + 42500096);
    unsigned long long* bits = (unsigned long long*)(w + 42532864);
    unsigned short* x_bf  = (unsigned short*)(w + 43581440);
    unsigned short* x2_bf = (unsigned short*)(w + 43581440);   // reuse after gemm1
    unsigned short* WhF   = (unsigned short*)(w + 49872896);
    unsigned short* WoF   = (unsigned short*)(w + 53018624);
    unsigned short* WlF   = (unsigned short*)(w + 54067200);
    unsigned short* WnF   = (unsigned short*)(w + 55115776);
    unsigned short* hfrag = (unsigned short*)(w + 55246848);   // 16 MB
    unsigned short* h2frag= (unsigned short*)(w + 72024064);   // 2 MB
    unsigned short* x1_bf = (unsigned short*)(w + 74121216);
    float* plsum = E1p_mh;

    // 0) prep
    adjbits_kernel<<<(Bb * Nn * Nn) / 256, 256, 0, stream>>>(adj, bits);
    cast_bf_kernel<<<(Bb * Nn * Ff) / 1024, 256, 0, stream>>>(x, x_bf);
    wfrag_kn_kernel<<<dim3(96, Hh), 256, 0, stream>>>(
        W_heads, WhF, Ff, Oo, (long long)Ff * Oo, 384LL * 512);
    wfrag_kn_kernel<<<dim3(256, 1), 256, 0, stream>>>(
        W_out, WoF, Hh * Oo, Oo, 0, 0);
    wfrag_nk_kernel<<<256, 256, 0, stream>>>(W_lin, WlF, Hh * Oo);
    wfrag_nk_kernel<<<32, 256, 0, stream>>>(W_ln, WnF, Oo);

    // 1) h = x @ W_heads -> hfrag + fused mh scores/exp
    gemm_bf_kernel<<<dim3(Nn / 64, 1, Bb * Hh), 256, 0, stream>>>(
        x_bf, Ff, (long long)Nn * Ff, 3, WhF, 384LL * 512, 7,
        nullptr, 0, hfrag, 524288, Nn, nullptr, 1,
        a_heads, 7, E1p_mh, E1n_mh, E2pn_mh);
    // 2) multihead attention + elu -> x1_bf  (bh-major grid: XCD = bh%8)
    attn_v7_kernel<2048, 0, 1><<<dim3(Bb * Hh, Nn / 64, 1), 256, 0, stream>>>(
        hfrag, (const unsigned*)bits, E1p_mh, E1n_mh, E2pn_mh,
        x1_bf, Hh * Oo, nullptr, nullptr, 3);
    // 3) fused dual GEMM: h2frag (+sh scores) and lin
    gemm_dual_kernel<<<dim3(Nn / 64, 2, Bb), 256, 0, stream>>>(
        x1_bf, Hh * Oo, (long long)Nn * Hh * Oo, WoF, h2frag, lin,
        a_out, E1p_sh, E1n_sh, E2pn_sh);
    // 4) single-head attention, 8-way j-split partials
    attn_v7_kernel<256, 1, 0><<<dim3(Nn / 64, Bb, 8), 256, 0, stream>>>(
        h2frag, (const unsigned*)bits, E1p_sh, E1n_sh, E2pn_sh,
        nullptr, 0, pacc, plsum, 0);
    // 5) combine -> x2_bf
    combine8_kernel<<<(Bb * Nn * 64) / 256, 256, 0, stream>>>(pacc, plsum, lin, b_lin, x2_bf);
    // 6) out = relu(x2 @ W_ln^T + b_ln)
    gemm_bf_kernel<<<dim3(Nn / 64, 1, Bb), 256, 0, stream>>>(
        x2_bf, Oo, (long long)Nn * Oo, 0, WnF, 0, 0,
        (float*)d_out, (long long)Nn * Oo, nullptr, 0, Nn, b_ln, 2,
        nullptr, 0, nullptr, nullptr, nullptr);
}

// Round 15
// 285.556 us; speedup vs baseline: 1.0359x; 1.0359x over previous
//
#include <hip/hip_runtime.h>
#include <hip/hip_bf16.h>

constexpr int Bb = 2, Nn = 2048, Ff = 768, Hh = 8, Oo = 256;

typedef __attribute__((ext_vector_type(8)))  short   short8;
typedef __attribute__((ext_vector_type(16))) float   f32x16;
typedef __attribute__((ext_vector_type(4)))  unsigned short ushort4_t;

__device__ inline unsigned short f2bf(float f) {
    unsigned u = __float_as_uint(f);
    u = (u + 0x7FFFu + ((u >> 16) & 1u)) >> 16;   // RNE
    return (unsigned short)u;
}

// ---------------- adjacency bitmask ----------------
__global__ __launch_bounds__(256) void adjbits_kernel(
        const float* __restrict__ adj, unsigned long long* __restrict__ bits) {
    size_t gid = (size_t)blockIdx.x * 256 + threadIdx.x;
    float v = adj[gid];
    unsigned long long m = __ballot(v > 0.f);
    if ((threadIdx.x & 63) == 0) bits[gid >> 6] = m;
}

// ---------------- f32 -> bf16 flat cast ----------------
__global__ __launch_bounds__(256) void cast_bf_kernel(
        const float* __restrict__ in, unsigned short* __restrict__ out) {
    size_t i = (size_t)blockIdx.x * 256 + threadIdx.x;
    float4 v = ((const float4*)in)[i];
    ushort4_t o;
    o.x = f2bf(v.x); o.y = f2bf(v.y); o.z = f2bf(v.z); o.w = f2bf(v.w);
    ((ushort4_t*)out)[i] = o;
}

// ======== B-fragment layout: frag id = nt32*(K/16)+kt, 1 KB each ========
__global__ __launch_bounds__(256) void wfrag_kn_kernel(
        const float* __restrict__ W, unsigned short* __restrict__ out,
        int K, int N, long long sW, long long sO) {
    W   += (size_t)blockIdx.y * sW;
    out += (size_t)blockIdx.y * sO;
    int t = threadIdx.x;
    int f = blockIdx.x * 4 + (t >> 6);
    int slot = t & 63, kh = slot >> 5, lm = slot & 31;
    int nfk = K >> 4;
    int nt = f / nfk, kt = f - nt * nfk;
    const float* wp = W + (size_t)(kt * 16 + kh * 8) * N + nt * 32 + lm;
    ushort4_t o0, o1;
    o0.x = f2bf(wp[0]);             o0.y = f2bf(wp[(size_t)N]);
    o0.z = f2bf(wp[2 * (size_t)N]); o0.w = f2bf(wp[3 * (size_t)N]);
    o1.x = f2bf(wp[4 * (size_t)N]); o1.y = f2bf(wp[5 * (size_t)N]);
    o1.z = f2bf(wp[6 * (size_t)N]); o1.w = f2bf(wp[7 * (size_t)N]);
    unsigned short* op = out + (size_t)f * 512 + slot * 8;
    *(ushort4_t*)op = o0;
    *(ushort4_t*)(op + 4) = o1;
}

__global__ __launch_bounds__(256) void wfrag_nk_kernel(
        const float* __restrict__ W, unsigned short* __restrict__ out, int K) {
    int t = threadIdx.x;
    int f = blockIdx.x * 4 + (t >> 6);
    int slot = t & 63, kh = slot >> 5, lm = slot & 31;
    int nfk = K >> 4;
    int nt = f / nfk, kt = f - nt * nfk;
    const float* wp = W + (size_t)(nt * 32 + lm) * K + kt * 16 + kh * 8;
    float4 a = *(const float4*)wp, b = *(const float4*)(wp + 4);
    ushort4_t o0, o1;
    o0.x = f2bf(a.x); o0.y = f2bf(a.y); o0.z = f2bf(a.z); o0.w = f2bf(a.w);
    o1.x = f2bf(b.x); o1.y = f2bf(b.y); o1.z = f2bf(b.z); o1.w = f2bf(b.w);
    unsigned short* op = out + (size_t)f * 512 + slot * 8;
    *(ushort4_t*)op = o0;
    *(ushort4_t*)(op + 4) = o1;
}

// ---------------- MFMA GEMM, BK=64, optional fused scores epilogue ----------------
__global__ __launch_bounds__(256) void gemm_bf_kernel(
        const unsigned short* __restrict__ A, int K, long long sA, int bAshift,
        const unsigned short* __restrict__ BF, long long sB, int bmask,
        float* __restrict__ C, long long sC,
        unsigned short* __restrict__ CF, long long sCF, int Mtot,
        const float* __restrict__ bias, int mode,
        const float* __restrict__ aall, int amask,
        float* __restrict__ E1p, float* __restrict__ E1n, float2* __restrict__ E2pn) {
    int z = blockIdx.z;
    A  += (size_t)(z >> bAshift) * sA;
    BF += (size_t)(z & bmask) * sB;
    if (C) C += (size_t)z * sC;
    if (CF) CF += (size_t)z * sCF;
    int m0 = blockIdx.x * 64;
    int t = threadIdx.x;
    int wv = t >> 6, lane = t & 63;
    int lm = lane & 31, kh = lane >> 5;
    int nfk = K >> 4;
    __shared__ __align__(16) unsigned short As[64][72];
    f32x16 acc[2][2] = {};
    int sr = t >> 2, sc2 = (t & 3) * 16;
    const unsigned short* ag  = A + (size_t)(m0 + sr) * K + sc2;
    const unsigned short* bg0 = BF + (size_t)(wv * 2) * nfk * 512;
    const unsigned short* bg1 = bg0 + (size_t)nfk * 512;
    for (int k0 = 0; k0 < K; k0 += 64) {
        *(short8*)&As[sr][sc2]     = *(const short8*)(ag + k0);
        *(short8*)&As[sr][sc2 + 8] = *(const short8*)(ag + k0 + 8);
        int kt0 = k0 >> 4;
        __syncthreads();
#pragma unroll
        for (int s = 0; s < 4; ++s) {
            short8 a0 = *(const short8*)&As[lm][s * 16 + kh * 8];
            short8 a1 = *(const short8*)&As[32 + lm][s * 16 + kh * 8];
            short8 b0 = *(const short8*)(bg0 + (size_t)(kt0 + s) * 512 + lane * 8);
            short8 b1 = *(const short8*)(bg1 + (size_t)(kt0 + s) * 512 + lane * 8);
            acc[0][0] = __builtin_amdgcn_mfma_f32_32x32x16_bf16(a0, b0, acc[0][0], 0, 0, 0);
            acc[0][1] = __builtin_amdgcn_mfma_f32_32x32x16_bf16(a0, b1, acc[0][1], 0, 0, 0);
            acc[1][0] = __builtin_amdgcn_mfma_f32_32x32x16_bf16(a1, b0, acc[1][0], 0, 0, 0);
            acc[1][1] = __builtin_amdgcn_mfma_f32_32x32x16_bf16(a1, b1, acc[1][1], 0, 0, 0);
        }
        __syncthreads();
    }
#pragma unroll
    for (int mt = 0; mt < 2; ++mt)
#pragma unroll
        for (int nt = 0; nt < 2; ++nt) {
            int colg = wv * 64 + nt * 32 + lm;
            float bv = (mode == 2) ? bias[colg] : 0.f;
            if (C) {
#pragma unroll
                for (int reg = 0; reg < 16; ++reg) {
                    int rl = mt * 32 + 4 * kh + (reg & 3) + 8 * (reg >> 2);
                    float v = acc[mt][nt][reg];
                    if (mode == 2) { v += bv; v = fmaxf(v, 0.f); }
                    C[(size_t)(m0 + rl) * 256 + colg] = v;
                }
            }
            if (mode == 1) {
#pragma unroll
                for (int q = 0; q < 4; ++q) {
                    int kt = m0 / 16 + mt * 2 + (q >> 1);
                    size_t fi = ((size_t)(colg >> 5) * (Mtot / 16) + kt) * 512 +
                                ((q & 1) * 32 + (colg & 31)) * 8 + kh * 4;
                    ushort4_t pk;
                    pk.x = f2bf(acc[mt][nt][q * 4 + 0]);
                    pk.y = f2bf(acc[mt][nt][q * 4 + 1]);
                    pk.z = f2bf(acc[mt][nt][q * 4 + 2]);
                    pk.w = f2bf(acc[mt][nt][q * 4 + 3]);
                    *(ushort4_t*)(CF + fi) = pk;
                }
            }
        }
    if (aall) {
        const float* av = aall + (size_t)(z & amask) * 512;
        float a1v0 = av[wv * 64 + lm],       a1v1 = av[wv * 64 + 32 + lm];
        float a2v0 = av[256 + wv * 64 + lm], a2v1 = av[256 + wv * 64 + 32 + lm];
        float* sbuf = (float*)As;
#pragma unroll
        for (int mt = 0; mt < 2; ++mt)
#pragma unroll
            for (int reg = 0; reg < 16; ++reg) {
                int rl = mt * 32 + 4 * kh + (reg & 3) + 8 * (reg >> 2);
                float v1 = acc[mt][0][reg] * a1v0 + acc[mt][1][reg] * a1v1;
                float v2 = acc[mt][0][reg] * a2v0 + acc[mt][1][reg] * a2v1;
#pragma unroll
                for (int m = 1; m <= 16; m <<= 1) {
                    v1 += __shfl_xor(v1, m, 64);
                    v2 += __shfl_xor(v2, m, 64);
                }
                if (lm == 0) { sbuf[rl * 8 + wv] = v1; sbuf[rl * 8 + 4 + wv] = v2; }
            }
        __syncthreads();
        if (t < 64) {
            float s1 = sbuf[t * 8] + sbuf[t * 8 + 1] + sbuf[t * 8 + 2] + sbuf[t * 8 + 3];
            float s2 = sbuf[t * 8 + 4] + sbuf[t * 8 + 5] + sbuf[t * 8 + 6] + sbuf[t * 8 + 7];
            size_t ei = (size_t)z * Nn + m0 + t;
            E1p[ei] = __expf(s1);
            E1n[ei] = __expf(0.2f * s1);
            E2pn[ei] = make_float2(__expf(s2), __expf(0.2f * s2));
        }
    }
}

// ---------------- dual MFMA GEMM, BK=64: x1 @ [WoF ; WlF]; ng0 + fused sh scores ----------------
__global__ __launch_bounds__(256) void gemm_dual_kernel(
        const unsigned short* __restrict__ A, int K, long long sA,
        const unsigned short* __restrict__ BF,
        unsigned short* __restrict__ h2f, float* __restrict__ lin,
        const float* __restrict__ a_out,
        float* __restrict__ E1p, float* __restrict__ E1n, float2* __restrict__ E2pn) {
    int b = blockIdx.z, ng = blockIdx.y;
    A += (size_t)b * sA;
    int nfk = K >> 4;
    BF += (size_t)ng * 8 * nfk * 512;
    int m0 = blockIdx.x * 64;
    int t = threadIdx.x;
    int wv = t >> 6, lane = t & 63;
    int lm = lane & 31, kh = lane >> 5;
    __shared__ __align__(16) unsigned short As[64][72];
    f32x16 acc[2][2] = {};
    int sr = t >> 2, sc2 = (t & 3) * 16;
    const unsigned short* ag  = A + (size_t)(m0 + sr) * K + sc2;
    const unsigned short* bg0 = BF + (size_t)(wv * 2) * nfk * 512;
    const unsigned short* bg1 = bg0 + (size_t)nfk * 512;
    for (int k0 = 0; k0 < K; k0 += 64) {
        *(short8*)&As[sr][sc2]     = *(const short8*)(ag + k0);
        *(short8*)&As[sr][sc2 + 8] = *(const short8*)(ag + k0 + 8);
        int kt0 = k0 >> 4;
        __syncthreads();
#pragma unroll
        for (int s = 0; s < 4; ++s) {
            short8 a0 = *(const short8*)&As[lm][s * 16 + kh * 8];
            short8 a1 = *(const short8*)&As[32 + lm][s * 16 + kh * 8];
            short8 b0 = *(const short8*)(bg0 + (size_t)(kt0 + s) * 512 + lane * 8);
            short8 b1 = *(const short8*)(bg1 + (size_t)(kt0 + s) * 512 + lane * 8);
            acc[0][0] = __builtin_amdgcn_mfma_f32_32x32x16_bf16(a0, b0, acc[0][0], 0, 0, 0);
            acc[0][1] = __builtin_amdgcn_mfma_f32_32x32x16_bf16(a0, b1, acc[0][1], 0, 0, 0);
            acc[1][0] = __builtin_amdgcn_mfma_f32_32x32x16_bf16(a1, b0, acc[1][0], 0, 0, 0);
            acc[1][1] = __builtin_amdgcn_mfma_f32_32x32x16_bf16(a1, b1, acc[1][1], 0, 0, 0);
        }
        __syncthreads();
    }
    if (ng == 1) {
        float* C = lin + (size_t)b * Nn * 256;
#pragma unroll
        for (int mt = 0; mt < 2; ++mt)
#pragma unroll
            for (int nt = 0; nt < 2; ++nt) {
                int colg = wv * 64 + nt * 32 + lm;
#pragma unroll
                for (int reg = 0; reg < 16; ++reg) {
                    int rl = mt * 32 + 4 * kh + (reg & 3) + 8 * (reg >> 2);
                    C[(size_t)(m0 + rl) * 256 + colg] = acc[mt][nt][reg];
                }
            }
    } else {
        unsigned short* CF = h2f + (size_t)b * 524288;
#pragma unroll
        for (int mt = 0; mt < 2; ++mt)
#pragma unroll
            for (int nt = 0; nt < 2; ++nt) {
                int colg = wv * 64 + nt * 32 + lm;
#pragma unroll
                for (int q = 0; q < 4; ++q) {
                    int kt = m0 / 16 + mt * 2 + (q >> 1);
                    size_t fi = ((size_t)(colg >> 5) * 128 + kt) * 512 +
                                ((q & 1) * 32 + (colg & 31)) * 8 + kh * 4;
                    ushort4_t pk;
                    pk.x = f2bf(acc[mt][nt][q * 4 + 0]);
                    pk.y = f2bf(acc[mt][nt][q * 4 + 1]);
                    pk.z = f2bf(acc[mt][nt][q * 4 + 2]);
                    pk.w = f2bf(acc[mt][nt][q * 4 + 3]);
                    *(ushort4_t*)(CF + fi) = pk;
                }
            }
        float a1v0 = a_out[wv * 64 + lm],       a1v1 = a_out[wv * 64 + 32 + lm];
        float a2v0 = a_out[256 + wv * 64 + lm], a2v1 = a_out[256 + wv * 64 + 32 + lm];
        float* sbuf = (float*)As;
#pragma unroll
        for (int mt = 0; mt < 2; ++mt)
#pragma unroll
            for (int reg = 0; reg < 16; ++reg) {
                int rl = mt * 32 + 4 * kh + (reg & 3) + 8 * (reg >> 2);
                float v1 = acc[mt][0][reg] * a1v0 + acc[mt][1][reg] * a1v1;
                float v2 = acc[mt][0][reg] * a2v0 + acc[mt][1][reg] * a2v1;
#pragma unroll
                for (int m = 1; m <= 16; m <<= 1) {
                    v1 += __shfl_xor(v1, m, 64);
                    v2 += __shfl_xor(v2, m, 64);
                }
                if (lm == 0) { sbuf[rl * 8 + wv] = v1; sbuf[rl * 8 + 4 + wv] = v2; }
            }
        __syncthreads();
        if (t < 64) {
            float s1 = sbuf[t * 8] + sbuf[t * 8 + 1] + sbuf[t * 8 + 2] + sbuf[t * 8 + 3];
            float s2 = sbuf[t * 8 + 4] + sbuf[t * 8 + 5] + sbuf[t * 8 + 6] + sbuf[t * 8 + 7];
            size_t ei = (size_t)b * Nn + m0 + t;
            E1p[ei] = __expf(s1);
            E1n[ei] = __expf(0.2f * s1);
            E2pn[ei] = make_float2(__expf(s2), __expf(0.2f * s2));
        }
    }
}

// ---------------- attention v8: 32 i-rows/block, 4 blocks/CU, frag B ----------------
// grid doubles vs v5 (it covers 32 rows). Wave: acc[2] (64 o-cols), all 32 rows.
// B prefetch: 1-step lookahead ping-pong (16 VGPR) per R9. P-compute: 8 p/thread/chunk.
template<int JLEN, int MODE, int SWAPXY>
__global__ __launch_bounds__(256, 4) void attn_v8_kernel(
        const unsigned short* __restrict__ hfrag,
        const unsigned* __restrict__ bits,
        const float* __restrict__ E1p, const float* __restrict__ E1n,
        const float2* __restrict__ E2pn,
        unsigned short* __restrict__ outbf, int ldo,
        float* __restrict__ pacc, float* __restrict__ plsum,
        int hshift) {
    constexpr int W = JLEN / 32, NC = JLEN / 64, ABS = W + 1;
    int it = SWAPXY ? blockIdx.y : blockIdx.x;
    int bh = SWAPXY ? blockIdx.x : blockIdx.y;
    int js = blockIdx.z;
    int b = bh >> hshift, hd = bh & ((1 << hshift) - 1);
    int i0 = it * 32, jbase = js * JLEN;
    int kt0 = js * (JLEN / 16);
    int t = threadIdx.x, lane = t & 63;
    int wv = t >> 6, lm = lane & 31, kh = lane >> 5;
    int ti = t & 31, jq = t >> 5;    // P-compute: 32 rows x 8 j-groups (8 j each)

    __shared__ unsigned ab[32 * ABS];
    __shared__ __align__(16) unsigned short ps[2][32][64];
    __shared__ float lred[32][9];
    __shared__ float linv[32];

    const unsigned* bb = bits + ((size_t)b * Nn + i0) * 64 + (jbase >> 5);
    for (int k = t; k < 32 * W; k += 256) {
        int r = k / W, w0 = k - r * W;
        ab[r * ABS + w0] = bb[(size_t)r * 64 + w0];
    }
    __syncthreads();   // ab[] must be visible before computeP

    float e1p = E1p[(size_t)bh * Nn + i0 + ti];
    float e1n = E1n[(size_t)bh * Nn + i0 + ti];
    const float4* e2base = (const float4*)(E2pn + (size_t)bh * Nn + jbase);

    const unsigned short* bg0 = hfrag + (size_t)bh * 524288 + (size_t)(wv * 2) * 128 * 512;
    const unsigned short* bg1 = bg0 + 128 * 512;

    f32x16 acc[2] = {};
    float lp0 = 0.f, lp1 = 0.f;
    short8 Bpp[2][2];   // [slot][nt] ping-pong

    auto loadBs = [&](int c, int s, int slot) {
        int kt = kt0 + c * 4 + s;
        Bpp[slot][0] = *(const short8*)(bg0 + (size_t)kt * 512 + lane * 8);
        Bpp[slot][1] = *(const short8*)(bg1 + (size_t)kt * 512 + lane * 8);
    };
    auto computeP = [&](int c, int buf) {
        int cj = c * 64;
        unsigned word = ab[ti * ABS + (cj >> 5) + (jq >> 2)];
        unsigned field = (word >> ((jq & 3) * 8)) & 0xffu;
        const float4* ep = e2base + ((cj + jq * 8) >> 1);
        unsigned pk[4];
#pragma unroll
        for (int u = 0; u < 4; ++u) {
            float4 q = ep[u];
            float p0 = fmaxf(e1p * q.x, e1n * q.y);   // select==max (exact)
            p0 = ((field >> (2 * u)) & 1u) ? p0 : 0.f;
            float p1 = fmaxf(e1p * q.z, e1n * q.w);
            p1 = ((field >> (2 * u + 1)) & 1u) ? p1 : 0.f;
            if (u & 1) lp1 += p0 + p1; else lp0 += p0 + p1;
            __hip_bfloat162 hv = __float22bfloat162_rn(make_float2(p0, p1));
            pk[u] = *(unsigned*)&hv;
        }
        uint4 v; v.x = pk[0]; v.y = pk[1]; v.z = pk[2]; v.w = pk[3];
        *(uint4*)&ps[buf][ti][(jq ^ (ti & 7)) * 8] = v;
    };
    auto mfmaS = [&](int buf, int s, int slot) {
        int g = 2 * s + kh;
        short8 a0 = *(const short8*)&ps[buf][lm][(g ^ (lm & 7)) * 8];
        acc[0] = __builtin_amdgcn_mfma_f32_32x32x16_bf16(a0, Bpp[slot][0], acc[0], 0, 0, 0);
        acc[1] = __builtin_amdgcn_mfma_f32_32x32x16_bf16(a0, Bpp[slot][1], acc[1], 0, 0, 0);
    };

    computeP(0, 0);
    loadBs(0, 0, 0);
    __syncthreads();
    for (int c = 0; c < NC; ++c) {
        int cb = c & 1, nb = cb ^ 1;
        if (c + 1 < NC) computeP(c + 1, nb);
        loadBs(c, 1, 1);            mfmaS(cb, 0, 0);
        loadBs(c, 2, 0);            mfmaS(cb, 1, 1);
        loadBs(c, 3, 1);            mfmaS(cb, 2, 0);
        if (c + 1 < NC) loadBs(c + 1, 0, 0);
        mfmaS(cb, 3, 1);
        __syncthreads();
    }

    lred[ti][jq] = lp0 + lp1;
    __syncthreads();
    if (MODE == 0) {
        if (t < 32) {
            float s = 0.f;
#pragma unroll
            for (int k = 0; k < 8; ++k) s += lred[t][k];
            linv[t] = 1.f / s;
        }
        __syncthreads();
#pragma unroll
        for (int nt = 0; nt < 2; ++nt) {
            int o = wv * 64 + nt * 32 + lm;
#pragma unroll
            for (int reg = 0; reg < 16; ++reg) {
                int rl = 4 * kh + (reg & 3) + 8 * (reg >> 2);
                float v = acc[nt][reg] * linv[rl];
                v = v > 0.f ? v : expm1f(v);   // elu (layer 1)
                outbf[((size_t)b * Nn + i0 + rl) * ldo + (size_t)hd * Oo + o] = f2bf(v);
            }
        }
    } else {
        if (t < 32) {
            float s = 0.f;
#pragma unroll
            for (int k = 0; k < 8; ++k) s += lred[t][k];
            plsum[((size_t)js * Bb + b) * Nn + i0 + t] = s;
        }
        float* pa = pacc + (((size_t)js * Bb + b) * Nn) * 256;
#pragma unroll
        for (int nt = 0; nt < 2; ++nt) {
            int o = wv * 64 + nt * 32 + lm;
#pragma unroll
            for (int reg = 0; reg < 16; ++reg) {
                int rl = 4 * kh + (reg & 3) + 8 * (reg >> 2);
                pa[(size_t)(i0 + rl) * 256 + o] = acc[nt][reg];
            }
        }
    }
}

// ---------------- combine 8 partials: x2 = Σacc/Σl + lin + b ----------------
__global__ __launch_bounds__(256) void combine8_kernel(
        const float* __restrict__ pacc, const float* __restrict__ plsum,
        const float* __restrict__ lin, const float* __restrict__ bias,
        unsigned short* __restrict__ out) {
    int gid = blockIdx.x * 256 + threadIdx.x;
    int row = gid >> 6;
    int o4 = gid & 63;
    size_t ps4 = (size_t)Bb * Nn * 64;
    const float4* p = (const float4*)pacc + (size_t)row * 64 + o4;
    float4 s = p[0];
#pragma unroll
    for (int k = 1; k < 8; ++k) {
        float4 q = p[k * ps4];
        s.x += q.x; s.y += q.y; s.z += q.z; s.w += q.w;
    }
    int BN = Bb * Nn;
    float lsum = 0.f;
#pragma unroll
    for (int k = 0; k < 8; ++k) lsum += plsum[row + k * BN];
    float li = 1.f / lsum;
    float4 lv = ((const float4*)lin)[(size_t)row * 64 + o4];
    float4 bv = ((const float4*)bias)[o4];
    float4 v;
    v.x = s.x * li + lv.x + bv.x; v.y = s.y * li + lv.y + bv.y;
    v.z = s.z * li + lv.z + bv.z; v.w = s.w * li + lv.w + bv.w;
    __hip_bfloat162 h0 = __float22bfloat162_rn(make_float2(v.x, v.y));
    __hip_bfloat162 h1 = __float22bfloat162_rn(make_float2(v.z, v.w));
    uint2 st; st.x = *(unsigned*)&h0; st.y = *(unsigned*)&h1;
    *(uint2*)(out + (size_t)gid * 4) = st;
}

extern "C" void kernel_launch(void* const* d_in, const int* in_sizes, int n_in,
                              void* d_out, int out_size, void* d_ws, size_t ws_size,
                              hipStream_t stream) {
    const float* x       = (const float*)d_in[0];
    const float* adj     = (const float*)d_in[1];
    const float* W_heads = (const float*)d_in[3];
    const float* a_heads = (const float*)d_in[4];
    const float* W_out   = (const float*)d_in[5];
    const float* a_out   = (const float*)d_in[6];
    const float* W_lin   = (const float*)d_in[7];
    const float* b_lin   = (const float*)d_in[8];
    const float* W_ln    = (const float*)d_in[9];
    const float* b_ln    = (const float*)d_in[10];

    char* w = (char*)d_ws;
    float* pacc     = (float*)(w);                    // 8x4 MB (sh partials)
    float* lin      = (float*)(w + 33554432);
    float* E1p_mh   = (float*)(w + 41943040);
    float* E1n_mh   = (float*)(w + 42074112);
    float2* E2pn_mh = (float2*)(w + 42205184);
    float* E1p_sh   = (float*)(w + 42467328);
    float* E1n_sh   = (float*)(w + 42483712);
    float2* E2pn_sh = (float2*)(w + 42500096);
    unsigned long long* bits = (unsigned long long*)(w + 42532864);
    unsigned short* x_bf  = (unsigned short*)(w + 43581440);
    unsigned short* x2_bf = (unsigned short*)(w + 43581440);   // reuse after gemm1
    unsigned short* WhF   = (unsigned short*)(w + 49872896);
    unsigned short* WoF   = (unsigned short*)(w + 53018624);
    unsigned short* WlF   = (unsigned short*)(w + 54067200);
    unsigned short* WnF   = (unsigned short*)(w + 55115776);
    unsigned short* hfrag = (unsigned short*)(w + 55246848);   // 16 MB
    unsigned short* h2frag= (unsigned short*)(w + 72024064);   // 2 MB
    unsigned short* x1_bf = (unsigned short*)(w + 74121216);
    float* plsum = E1p_mh;

    // 0) prep
    adjbits_kernel<<<(Bb * Nn * Nn) / 256, 256, 0, stream>>>(adj, bits);
    cast_bf_kernel<<<(Bb * Nn * Ff) / 1024, 256, 0, stream>>>(x, x_bf);
    wfrag_kn_kernel<<<dim3(96, Hh), 256, 0, stream>>>(
        W_heads, WhF, Ff, Oo, (long long)Ff * Oo, 384LL * 512);
    wfrag_kn_kernel<<<dim3(256, 1), 256, 0, stream>>>(
        W_out, WoF, Hh * Oo, Oo, 0, 0);
    wfrag_nk_kernel<<<256, 256, 0, stream>>>(W_lin, WlF, Hh * Oo);
    wfrag_nk_kernel<<<32, 256, 0, stream>>>(W_ln, WnF, Oo);

    // 1) h = x @ W_heads -> hfrag + fused mh scores/exp
    gemm_bf_kernel<<<dim3(Nn / 64, 1, Bb * Hh), 256, 0, stream>>>(
        x_bf, Ff, (long long)Nn * Ff, 3, WhF, 384LL * 512, 7,
        nullptr, 0, hfrag, 524288, Nn, nullptr, 1,
        a_heads, 7, E1p_mh, E1n_mh, E2pn_mh);
    // 2) multihead attention + elu -> x1_bf  (32-row tiles: 1024 blocks = 4/CU; XCD = bh%8)
    attn_v8_kernel<2048, 0, 1><<<dim3(Bb * Hh, Nn / 32, 1), 256, 0, stream>>>(
        hfrag, (const unsigned*)bits, E1p_mh, E1n_mh, E2pn_mh,
        x1_bf, Hh * Oo, nullptr, nullptr, 3);
    // 3) fused dual GEMM: h2frag (+sh scores) and lin
    gemm_dual_kernel<<<dim3(Nn / 64, 2, Bb), 256, 0, stream>>>(
        x1_bf, Hh * Oo, (long long)Nn * Hh * Oo, WoF, h2frag, lin,
        a_out, E1p_sh, E1n_sh, E2pn_sh);
    // 4) single-head attention, 8-way j-split partials (32-row tiles: 1024 blocks)
    attn_v8_kernel<256, 1, 0><<<dim3(Nn / 32, Bb, 8), 256, 0, stream>>>(
        h2frag, (const unsigned*)bits, E1p_sh, E1n_sh, E2pn_sh,
        nullptr, 0, pacc, plsum, 0);
    // 5) combine -> x2_bf
    combine8_kernel<<<(Bb * Nn * 64) / 256, 256, 0, stream>>>(pacc, plsum, lin, b_lin, x2_bf);
    // 6) out = relu(x2 @ W_ln^T + b_ln)
    gemm_bf_kernel<<<dim3(Nn / 64, 1, Bb), 256, 0, stream>>>(
        x2_bf, Oo, (long long)Nn * Oo, 0, WnF, 0, 0,
        (float*)d_out, (long long)Nn * Oo, nullptr, 0, Nn, b_ln, 2,
        nullptr, 0, nullptr, nullptr, nullptr);
}

// Round 16
// 280.884 us; speedup vs baseline: 1.0531x; 1.0166x over previous
//
#include <hip/hip_runtime.h>
#include <hip/hip_bf16.h>

constexpr int Bb = 2, Nn = 2048, Ff = 768, Hh = 8, Oo = 256;

typedef __attribute__((ext_vector_type(8)))  short   short8;
typedef __attribute__((ext_vector_type(16))) float   f32x16;
typedef __attribute__((ext_vector_type(4)))  unsigned short ushort4_t;

__device__ inline unsigned short f2bf(float f) {
    unsigned u = __float_as_uint(f);
    u = (u + 0x7FFFu + ((u >> 16) & 1u)) >> 16;   // RNE
    return (unsigned short)u;
}

// ---------------- adjacency bitmask ----------------
__global__ __launch_bounds__(256) void adjbits_kernel(
        const float* __restrict__ adj, unsigned long long* __restrict__ bits) {
    size_t gid = (size_t)blockIdx.x * 256 + threadIdx.x;
    float v = adj[gid];
    unsigned long long m = __ballot(v > 0.f);
    if ((threadIdx.x & 63) == 0) bits[gid >> 6] = m;
}

// ---------------- f32 -> bf16 flat cast ----------------
__global__ __launch_bounds__(256) void cast_bf_kernel(
        const float* __restrict__ in, unsigned short* __restrict__ out) {
    size_t i = (size_t)blockIdx.x * 256 + threadIdx.x;
    float4 v = ((const float4*)in)[i];
    ushort4_t o;
    o.x = f2bf(v.x); o.y = f2bf(v.y); o.z = f2bf(v.z); o.w = f2bf(v.w);
    ((ushort4_t*)out)[i] = o;
}

// ======== B-fragment layout: frag id = nt32*(K/16)+kt, 1 KB each ========
__global__ __launch_bounds__(256) void wfrag_kn_kernel(
        const float* __restrict__ W, unsigned short* __restrict__ out,
        int K, int N, long long sW, long long sO) {
    W   += (size_t)blockIdx.y * sW;
    out += (size_t)blockIdx.y * sO;
    int t = threadIdx.x;
    int f = blockIdx.x * 4 + (t >> 6);
    int slot = t & 63, kh = slot >> 5, lm = slot & 31;
    int nfk = K >> 4;
    int nt = f / nfk, kt = f - nt * nfk;
    const float* wp = W + (size_t)(kt * 16 + kh * 8) * N + nt * 32 + lm;
    ushort4_t o0, o1;
    o0.x = f2bf(wp[0]);             o0.y = f2bf(wp[(size_t)N]);
    o0.z = f2bf(wp[2 * (size_t)N]); o0.w = f2bf(wp[3 * (size_t)N]);
    o1.x = f2bf(wp[4 * (size_t)N]); o1.y = f2bf(wp[5 * (size_t)N]);
    o1.z = f2bf(wp[6 * (size_t)N]); o1.w = f2bf(wp[7 * (size_t)N]);
    unsigned short* op = out + (size_t)f * 512 + slot * 8;
    *(ushort4_t*)op = o0;
    *(ushort4_t*)(op + 4) = o1;
}

__global__ __launch_bounds__(256) void wfrag_nk_kernel(
        const float* __restrict__ W, unsigned short* __restrict__ out, int K) {
    int t = threadIdx.x;
    int f = blockIdx.x * 4 + (t >> 6);
    int slot = t & 63, kh = slot >> 5, lm = slot & 31;
    int nfk = K >> 4;
    int nt = f / nfk, kt = f - nt * nfk;
    const float* wp = W + (size_t)(nt * 32 + lm) * K + kt * 16 + kh * 8;
    float4 a = *(const float4*)wp, b = *(const float4*)(wp + 4);
    ushort4_t o0, o1;
    o0.x = f2bf(a.x); o0.y = f2bf(a.y); o0.z = f2bf(a.z); o0.w = f2bf(a.w);
    o1.x = f2bf(b.x); o1.y = f2bf(b.y); o1.z = f2bf(b.z); o1.w = f2bf(b.w);
    unsigned short* op = out + (size_t)f * 512 + slot * 8;
    *(ushort4_t*)op = o0;
    *(ushort4_t*)(op + 4) = o1;
}

// ---------------- 32-row-tile MFMA GEMM, BK=64 ----------------
// wave: 32m x 64n (acc[2]); block: 32m x 256n. SWAPZ=1: blockIdx.x=z, .y=mtile.
// mode 1: bf16 frag CF (+opt f32 C) + fused scores if aall. mode 2: bias+relu C.
template<int SWAPZ>
__global__ __launch_bounds__(256) void gemm32_kernel(
        const unsigned short* __restrict__ A, int K, long long sA, int bAshift,
        const unsigned short* __restrict__ BF, long long sB, int bmask,
        float* __restrict__ C, long long sC,
        unsigned short* __restrict__ CF, long long sCF, int Mtot,
        const float* __restrict__ bias, int mode,
        const float* __restrict__ aall, int amask,
        float* __restrict__ E1p, float* __restrict__ E1n, float2* __restrict__ E2pn) {
    int z  = SWAPZ ? blockIdx.x : blockIdx.z;
    int mx = SWAPZ ? blockIdx.y : blockIdx.x;
    A  += (size_t)(z >> bAshift) * sA;
    BF += (size_t)(z & bmask) * sB;
    if (C) C += (size_t)z * sC;
    if (CF) CF += (size_t)z * sCF;
    int m0 = mx * 32;
    int t = threadIdx.x;
    int wv = t >> 6, lane = t & 63;
    int lm = lane & 31, kh = lane >> 5;
    int nfk = K >> 4;
    __shared__ __align__(16) unsigned short As[32][72];
    f32x16 acc[2] = {};
    int sr = t >> 3, sc2 = (t & 7) * 8;
    const unsigned short* ag  = A + (size_t)(m0 + sr) * K + sc2;
    const unsigned short* bg0 = BF + (size_t)(wv * 2) * nfk * 512;
    const unsigned short* bg1 = bg0 + (size_t)nfk * 512;
    for (int k0 = 0; k0 < K; k0 += 64) {
        *(short8*)&As[sr][sc2] = *(const short8*)(ag + k0);
        int kt0 = k0 >> 4;
        __syncthreads();
#pragma unroll
        for (int s = 0; s < 4; ++s) {
            short8 a0 = *(const short8*)&As[lm][s * 16 + kh * 8];
            short8 b0 = *(const short8*)(bg0 + (size_t)(kt0 + s) * 512 + lane * 8);
            short8 b1 = *(const short8*)(bg1 + (size_t)(kt0 + s) * 512 + lane * 8);
            acc[0] = __builtin_amdgcn_mfma_f32_32x32x16_bf16(a0, b0, acc[0], 0, 0, 0);
            acc[1] = __builtin_amdgcn_mfma_f32_32x32x16_bf16(a0, b1, acc[1], 0, 0, 0);
        }
        __syncthreads();
    }
#pragma unroll
    for (int nt = 0; nt < 2; ++nt) {
        int colg = wv * 64 + nt * 32 + lm;
        float bv = (mode == 2) ? bias[colg] : 0.f;
        if (C) {
#pragma unroll
            for (int reg = 0; reg < 16; ++reg) {
                int rl = 4 * kh + (reg & 3) + 8 * (reg >> 2);
                float v = acc[nt][reg];
                if (mode == 2) { v += bv; v = fmaxf(v, 0.f); }
                C[(size_t)(m0 + rl) * 256 + colg] = v;
            }
        }
        if (mode == 1) {
#pragma unroll
            for (int q = 0; q < 4; ++q) {
                int kt = m0 / 16 + (q >> 1);
                size_t fi = ((size_t)(colg >> 5) * (Mtot / 16) + kt) * 512 +
                            ((q & 1) * 32 + (colg & 31)) * 8 + kh * 4;
                ushort4_t pk;
                pk.x = f2bf(acc[nt][q * 4 + 0]);
                pk.y = f2bf(acc[nt][q * 4 + 1]);
                pk.z = f2bf(acc[nt][q * 4 + 2]);
                pk.w = f2bf(acc[nt][q * 4 + 3]);
                *(ushort4_t*)(CF + fi) = pk;
            }
        }
    }
    if (aall) {
        const float* av = aall + (size_t)(z & amask) * 512;
        float a1v0 = av[wv * 64 + lm],       a1v1 = av[wv * 64 + 32 + lm];
        float a2v0 = av[256 + wv * 64 + lm], a2v1 = av[256 + wv * 64 + 32 + lm];
        float* sbuf = (float*)As;   // dead after K-loop; [row][8]
#pragma unroll
        for (int reg = 0; reg < 16; ++reg) {
            int rl = 4 * kh + (reg & 3) + 8 * (reg >> 2);
            float v1 = acc[0][reg] * a1v0 + acc[1][reg] * a1v1;
            float v2 = acc[0][reg] * a2v0 + acc[1][reg] * a2v1;
#pragma unroll
            for (int m = 1; m <= 16; m <<= 1) {
                v1 += __shfl_xor(v1, m, 64);
                v2 += __shfl_xor(v2, m, 64);
            }
            if (lm == 0) { sbuf[rl * 8 + wv] = v1; sbuf[rl * 8 + 4 + wv] = v2; }
        }
        __syncthreads();
        if (t < 32) {
            float s1 = sbuf[t * 8] + sbuf[t * 8 + 1] + sbuf[t * 8 + 2] + sbuf[t * 8 + 3];
            float s2 = sbuf[t * 8 + 4] + sbuf[t * 8 + 5] + sbuf[t * 8 + 6] + sbuf[t * 8 + 7];
            size_t ei = (size_t)z * Nn + m0 + t;
            E1p[ei] = __expf(s1);
            E1n[ei] = __expf(0.2f * s1);
            E2pn[ei] = make_float2(__expf(s2), __expf(0.2f * s2));
        }
    }
}

// ---------------- 32-row dual GEMM: x1 @ [WoF ; WlF]; ng0 + fused sh scores ----------------
__global__ __launch_bounds__(256) void gemm32_dual_kernel(
        const unsigned short* __restrict__ A, int K, long long sA,
        const unsigned short* __restrict__ BF,
        unsigned short* __restrict__ h2f, float* __restrict__ lin,
        const float* __restrict__ a_out,
        float* __restrict__ E1p, float* __restrict__ E1n, float2* __restrict__ E2pn) {
    int b = blockIdx.z, ng = blockIdx.y;
    A += (size_t)b * sA;
    int nfk = K >> 4;   // 128
    BF += (size_t)ng * 8 * nfk * 512;
    int m0 = blockIdx.x * 32;
    int t = threadIdx.x;
    int wv = t >> 6, lane = t & 63;
    int lm = lane & 31, kh = lane >> 5;
    __shared__ __align__(16) unsigned short As[32][72];
    f32x16 acc[2] = {};
    int sr = t >> 3, sc2 = (t & 7) * 8;
    const unsigned short* ag  = A + (size_t)(m0 + sr) * K + sc2;
    const unsigned short* bg0 = BF + (size_t)(wv * 2) * nfk * 512;
    const unsigned short* bg1 = bg0 + (size_t)nfk * 512;
    for (int k0 = 0; k0 < K; k0 += 64) {
        *(short8*)&As[sr][sc2] = *(const short8*)(ag + k0);
        int kt0 = k0 >> 4;
        __syncthreads();
#pragma unroll
        for (int s = 0; s < 4; ++s) {
            short8 a0 = *(const short8*)&As[lm][s * 16 + kh * 8];
            short8 b0 = *(const short8*)(bg0 + (size_t)(kt0 + s) * 512 + lane * 8);
            short8 b1 = *(const short8*)(bg1 + (size_t)(kt0 + s) * 512 + lane * 8);
            acc[0] = __builtin_amdgcn_mfma_f32_32x32x16_bf16(a0, b0, acc[0], 0, 0, 0);
            acc[1] = __builtin_amdgcn_mfma_f32_32x32x16_bf16(a0, b1, acc[1], 0, 0, 0);
        }
        __syncthreads();
    }
    if (ng == 1) {
        float* C = lin + (size_t)b * Nn * 256;
#pragma unroll
        for (int nt = 0; nt < 2; ++nt) {
            int colg = wv * 64 + nt * 32 + lm;
#pragma unroll
            for (int reg = 0; reg < 16; ++reg) {
                int rl = 4 * kh + (reg & 3) + 8 * (reg >> 2);
                C[(size_t)(m0 + rl) * 256 + colg] = acc[nt][reg];
            }
        }
    } else {
        unsigned short* CF = h2f + (size_t)b * 524288;
#pragma unroll
        for (int nt = 0; nt < 2; ++nt) {
            int colg = wv * 64 + nt * 32 + lm;
#pragma unroll
            for (int q = 0; q < 4; ++q) {
                int kt = m0 / 16 + (q >> 1);
                size_t fi = ((size_t)(colg >> 5) * 128 + kt) * 512 +
                            ((q & 1) * 32 + (colg & 31)) * 8 + kh * 4;
                ushort4_t pk;
                pk.x = f2bf(acc[nt][q * 4 + 0]);
                pk.y = f2bf(acc[nt][q * 4 + 1]);
                pk.z = f2bf(acc[nt][q * 4 + 2]);
                pk.w = f2bf(acc[nt][q * 4 + 3]);
                *(ushort4_t*)(CF + fi) = pk;
            }
        }
        float a1v0 = a_out[wv * 64 + lm],       a1v1 = a_out[wv * 64 + 32 + lm];
        float a2v0 = a_out[256 + wv * 64 + lm], a2v1 = a_out[256 + wv * 64 + 32 + lm];
        float* sbuf = (float*)As;
#pragma unroll
        for (int reg = 0; reg < 16; ++reg) {
            int rl = 4 * kh + (reg & 3) + 8 * (reg >> 2);
            float v1 = acc[0][reg] * a1v0 + acc[1][reg] * a1v1;
            float v2 = acc[0][reg] * a2v0 + acc[1][reg] * a2v1;
#pragma unroll
            for (int m = 1; m <= 16; m <<= 1) {
                v1 += __shfl_xor(v1, m, 64);
                v2 += __shfl_xor(v2, m, 64);
            }
            if (lm == 0) { sbuf[rl * 8 + wv] = v1; sbuf[rl * 8 + 4 + wv] = v2; }
        }
        __syncthreads();
        if (t < 32) {
            float s1 = sbuf[t * 8] + sbuf[t * 8 + 1] + sbuf[t * 8 + 2] + sbuf[t * 8 + 3];
            float s2 = sbuf[t * 8 + 4] + sbuf[t * 8 + 5] + sbuf[t * 8 + 6] + sbuf[t * 8 + 7];
            size_t ei = (size_t)b * Nn + m0 + t;
            E1p[ei] = __expf(s1);
            E1n[ei] = __expf(0.2f * s1);
            E2pn[ei] = make_float2(__expf(s2), __expf(0.2f * s2));
        }
    }
}

// ---------------- attention v8: 32 i-rows/block, frag B (R15 verified) ----------------
template<int JLEN, int MODE, int SWAPXY>
__global__ __launch_bounds__(256, 4) void attn_v8_kernel(
        const unsigned short* __restrict__ hfrag,
        const unsigned* __restrict__ bits,
        const float* __restrict__ E1p, const float* __restrict__ E1n,
        const float2* __restrict__ E2pn,
        unsigned short* __restrict__ outbf, int ldo,
        float* __restrict__ pacc, float* __restrict__ plsum,
        int hshift) {
    constexpr int W = JLEN / 32, NC = JLEN / 64, ABS = W + 1;
    int it = SWAPXY ? blockIdx.y : blockIdx.x;
    int bh = SWAPXY ? blockIdx.x : blockIdx.y;
    int js = blockIdx.z;
    int b = bh >> hshift, hd = bh & ((1 << hshift) - 1);
    int i0 = it * 32, jbase = js * JLEN;
    int kt0 = js * (JLEN / 16);
    int t = threadIdx.x, lane = t & 63;
    int wv = t >> 6, lm = lane & 31, kh = lane >> 5;
    int ti = t & 31, jq = t >> 5;

    __shared__ unsigned ab[32 * ABS];
    __shared__ __align__(16) unsigned short ps[2][32][64];
    __shared__ float lred[32][9];
    __shared__ float linv[32];

    const unsigned* bb = bits + ((size_t)b * Nn + i0) * 64 + (jbase >> 5);
    for (int k = t; k < 32 * W; k += 256) {
        int r = k / W, w0 = k - r * W;
        ab[r * ABS + w0] = bb[(size_t)r * 64 + w0];
    }
    __syncthreads();   // ab[] must be visible before computeP

    float e1p = E1p[(size_t)bh * Nn + i0 + ti];
    float e1n = E1n[(size_t)bh * Nn + i0 + ti];
    const float4* e2base = (const float4*)(E2pn + (size_t)bh * Nn + jbase);

    const unsigned short* bg0 = hfrag + (size_t)bh * 524288 + (size_t)(wv * 2) * 128 * 512;
    const unsigned short* bg1 = bg0 + 128 * 512;

    f32x16 acc[2] = {};
    float lp0 = 0.f, lp1 = 0.f;
    short8 Bpp[2][2];

    auto loadBs = [&](int c, int s, int slot) {
        int kt = kt0 + c * 4 + s;
        Bpp[slot][0] = *(const short8*)(bg0 + (size_t)kt * 512 + lane * 8);
        Bpp[slot][1] = *(const short8*)(bg1 + (size_t)kt * 512 + lane * 8);
    };
    auto computeP = [&](int c, int buf) {
        int cj = c * 64;
        unsigned word = ab[ti * ABS + (cj >> 5) + (jq >> 2)];
        unsigned field = (word >> ((jq & 3) * 8)) & 0xffu;
        const float4* ep = e2base + ((cj + jq * 8) >> 1);
        unsigned pk[4];
#pragma unroll
        for (int u = 0; u < 4; ++u) {
            float4 q = ep[u];
            float p0 = fmaxf(e1p * q.x, e1n * q.y);   // select==max (exact)
            p0 = ((field >> (2 * u)) & 1u) ? p0 : 0.f;
            float p1 = fmaxf(e1p * q.z, e1n * q.w);
            p1 = ((field >> (2 * u + 1)) & 1u) ? p1 : 0.f;
            if (u & 1) lp1 += p0 + p1; else lp0 += p0 + p1;
            __hip_bfloat162 hv = __float22bfloat162_rn(make_float2(p0, p1));
            pk[u] = *(unsigned*)&hv;
        }
        uint4 v; v.x = pk[0]; v.y = pk[1]; v.z = pk[2]; v.w = pk[3];
        *(uint4*)&ps[buf][ti][(jq ^ (ti & 7)) * 8] = v;
    };
    auto mfmaS = [&](int buf, int s, int slot) {
        int g = 2 * s + kh;
        short8 a0 = *(const short8*)&ps[buf][lm][(g ^ (lm & 7)) * 8];
        acc[0] = __builtin_amdgcn_mfma_f32_32x32x16_bf16(a0, Bpp[slot][0], acc[0], 0, 0, 0);
        acc[1] = __builtin_amdgcn_mfma_f32_32x32x16_bf16(a0, Bpp[slot][1], acc[1], 0, 0, 0);
    };

    computeP(0, 0);
    loadBs(0, 0, 0);
    __syncthreads();
    for (int c = 0; c < NC; ++c) {
        int cb = c & 1, nb = cb ^ 1;
        if (c + 1 < NC) computeP(c + 1, nb);
        loadBs(c, 1, 1);            mfmaS(cb, 0, 0);
        loadBs(c, 2, 0);            mfmaS(cb, 1, 1);
        loadBs(c, 3, 1);            mfmaS(cb, 2, 0);
        if (c + 1 < NC) loadBs(c + 1, 0, 0);
        mfmaS(cb, 3, 1);
        __syncthreads();
    }

    lred[ti][jq] = lp0 + lp1;
    __syncthreads();
    if (MODE == 0) {
        if (t < 32) {
            float s = 0.f;
#pragma unroll
            for (int k = 0; k < 8; ++k) s += lred[t][k];
            linv[t] = 1.f / s;
        }
        __syncthreads();
#pragma unroll
        for (int nt = 0; nt < 2; ++nt) {
            int o = wv * 64 + nt * 32 + lm;
#pragma unroll
            for (int reg = 0; reg < 16; ++reg) {
                int rl = 4 * kh + (reg & 3) + 8 * (reg >> 2);
                float v = acc[nt][reg] * linv[rl];
                v = v > 0.f ? v : expm1f(v);   // elu (layer 1)
                outbf[((size_t)b * Nn + i0 + rl) * ldo + (size_t)hd * Oo + o] = f2bf(v);
            }
        }
    } else {
        if (t < 32) {
            float s = 0.f;
#pragma unroll
            for (int k = 0; k < 8; ++k) s += lred[t][k];
            plsum[((size_t)js * Bb + b) * Nn + i0 + t] = s;
        }
        float* pa = pacc + (((size_t)js * Bb + b) * Nn) * 256;
#pragma unroll
        for (int nt = 0; nt < 2; ++nt) {
            int o = wv * 64 + nt * 32 + lm;
#pragma unroll
            for (int reg = 0; reg < 16; ++reg) {
                int rl = 4 * kh + (reg & 3) + 8 * (reg >> 2);
                pa[(size_t)(i0 + rl) * 256 + o] = acc[nt][reg];
            }
        }
    }
}

// ---------------- combine 4 partials: x2 = Σacc/Σl + lin + b ----------------
__global__ __launch_bounds__(256) void combine4_kernel(
        const float* __restrict__ pacc, const float* __restrict__ plsum,
        const float* __restrict__ lin, const float* __restrict__ bias,
        unsigned short* __restrict__ out) {
    int gid = blockIdx.x * 256 + threadIdx.x;
    int row = gid >> 6;
    int o4 = gid & 63;
    size_t ps4 = (size_t)Bb * Nn * 64;
    const float4* p = (const float4*)pacc + (size_t)row * 64 + o4;
    float4 s = p[0];
#pragma unroll
    for (int k = 1; k < 4; ++k) {
        float4 q = p[k * ps4];
        s.x += q.x; s.y += q.y; s.z += q.z; s.w += q.w;
    }
    int BN = Bb * Nn;
    float lsum = 0.f;
#pragma unroll
    for (int k = 0; k < 4; ++k) lsum += plsum[row + k * BN];
    float li = 1.f / lsum;
    float4 lv = ((const float4*)lin)[(size_t)row * 64 + o4];
    float4 bv = ((const float4*)bias)[o4];
    float4 v;
    v.x = s.x * li + lv.x + bv.x; v.y = s.y * li + lv.y + bv.y;
    v.z = s.z * li + lv.z + bv.z; v.w = s.w * li + lv.w + bv.w;
    __hip_bfloat162 h0 = __float22bfloat162_rn(make_float2(v.x, v.y));
    __hip_bfloat162 h1 = __float22bfloat162_rn(make_float2(v.z, v.w));
    uint2 st; st.x = *(unsigned*)&h0; st.y = *(unsigned*)&h1;
    *(uint2*)(out + (size_t)gid * 4) = st;
}

extern "C" void kernel_launch(void* const* d_in, const int* in_sizes, int n_in,
                              void* d_out, int out_size, void* d_ws, size_t ws_size,
                              hipStream_t stream) {
    const float* x       = (const float*)d_in[0];
    const float* adj     = (const float*)d_in[1];
    const float* W_heads = (const float*)d_in[3];
    const float* a_heads = (const float*)d_in[4];
    const float* W_out   = (const float*)d_in[5];
    const float* a_out   = (const float*)d_in[6];
    const float* W_lin   = (const float*)d_in[7];
    const float* b_lin   = (const float*)d_in[8];
    const float* W_ln    = (const float*)d_in[9];
    const float* b_ln    = (const float*)d_in[10];

    char* w = (char*)d_ws;
    float* pacc     = (float*)(w);                    // 4x4 MB (sh partials)
    float* lin      = (float*)(w + 33554432);
    float* E1p_mh   = (float*)(w + 41943040);
    float* E1n_mh   = (float*)(w + 42074112);
    float2* E2pn_mh = (float2*)(w + 42205184);
    float* E1p_sh   = (float*)(w + 42467328);
    float* E1n_sh   = (float*)(w + 42483712);
    float2* E2pn_sh = (float2*)(w + 42500096);
    unsigned long long* bits = (unsigned long long*)(w + 42532864);
    unsigned short* x_bf  = (unsigned short*)(w + 43581440);
    unsigned short* x2_bf = (unsigned short*)(w + 43581440);   // reuse after gemm1
    unsigned short* WhF   = (unsigned short*)(w + 49872896);
    unsigned short* WoF   = (unsigned short*)(w + 53018624);
    unsigned short* WlF   = (unsigned short*)(w + 54067200);
    unsigned short* WnF   = (unsigned short*)(w + 55115776);
    unsigned short* hfrag = (unsigned short*)(w + 55246848);   // 16 MB
    unsigned short* h2frag= (unsigned short*)(w + 72024064);   // 2 MB
    unsigned short* x1_bf = (unsigned short*)(w + 74121216);
    float* plsum = E1p_mh;

    // 0) prep
    adjbits_kernel<<<(Bb * Nn * Nn) / 256, 256, 0, stream>>>(adj, bits);
    cast_bf_kernel<<<(Bb * Nn * Ff) / 1024, 256, 0, stream>>>(x, x_bf);
    wfrag_kn_kernel<<<dim3(96, Hh), 256, 0, stream>>>(
        W_heads, WhF, Ff, Oo, (long long)Ff * Oo, 384LL * 512);
    wfrag_kn_kernel<<<dim3(256, 1), 256, 0, stream>>>(
        W_out, WoF, Hh * Oo, Oo, 0, 0);
    wfrag_nk_kernel<<<256, 256, 0, stream>>>(W_lin, WlF, Hh * Oo);
    wfrag_nk_kernel<<<32, 256, 0, stream>>>(W_ln, WnF, Oo);

    // 1) h = x @ W_heads -> hfrag + fused mh scores/exp
    //    32-row tiles, z-major grid: 1024 blocks, XCD = z%8 pins WhF head-pair per L2.
    gemm32_kernel<1><<<dim3(Bb * Hh, Nn / 32, 1), 256, 0, stream>>>(
        x_bf, Ff, (long long)Nn * Ff, 3, WhF, 384LL * 512, 7,
        nullptr, 0, hfrag, 524288, Nn, nullptr, 1,
        a_heads, 7, E1p_mh, E1n_mh, E2pn_mh);
    // 2) multihead attention + elu -> x1_bf  (32-row tiles, XCD = bh%8)
    attn_v8_kernel<2048, 0, 1><<<dim3(Bb * Hh, Nn / 32, 1), 256, 0, stream>>>(
        hfrag, (const unsigned*)bits, E1p_mh, E1n_mh, E2pn_mh,
        x1_bf, Hh * Oo, nullptr, nullptr, 3);
    // 3) fused dual GEMM (32-row tiles, 256 blocks): h2frag (+sh scores) and lin
    gemm32_dual_kernel<<<dim3(Nn / 32, 2, Bb), 256, 0, stream>>>(
        x1_bf, Hh * Oo, (long long)Nn * Hh * Oo, WoF, h2frag, lin,
        a_out, E1p_sh, E1n_sh, E2pn_sh);
    // 4) single-head attention, 4-way j-split partials (512 blocks, 16 MB partials)
    attn_v8_kernel<512, 1, 0><<<dim3(Nn / 32, Bb, 4), 256, 0, stream>>>(
        h2frag, (const unsigned*)bits, E1p_sh, E1n_sh, E2pn_sh,
        nullptr, 0, pacc, plsum, 0);
    // 5) combine -> x2_bf
    combine4_kernel<<<(Bb * Nn * 64) / 256, 256, 0, stream>>>(pacc, plsum, lin, b_lin, x2_bf);
    // 6) out = relu(x2 @ W_ln^T + b_ln)  (32-row tiles, 128 blocks)
    gemm32_kernel<0><<<dim3(Nn / 32, 1, Bb), 256, 0, stream>>>(
        x2_bf, Oo, (long long)Nn * Oo, 0, WnF, 0, 0,
        (float*)d_out, (long long)Nn * Oo, nullptr, 0, Nn, b_ln, 2,
        nullptr, 0, nullptr, nullptr, nullptr);
}

// Round 17
// 273.353 us; speedup vs baseline: 1.0821x; 1.0275x over previous
//
#include <hip/hip_runtime.h>
#include <hip/hip_bf16.h>

constexpr int Bb = 2, Nn = 2048, Ff = 768, Hh = 8, Oo = 256;

typedef __attribute__((ext_vector_type(8)))  short   short8;
typedef __attribute__((ext_vector_type(16))) float   f32x16;
typedef __attribute__((ext_vector_type(4)))  unsigned short ushort4_t;

__device__ inline unsigned short f2bf(float f) {
    unsigned u = __float_as_uint(f);
    u = (u + 0x7FFFu + ((u >> 16) & 1u)) >> 16;   // RNE
    return (unsigned short)u;
}

// ---------------- adjacency bitmask ----------------
__global__ __launch_bounds__(256) void adjbits_kernel(
        const float* __restrict__ adj, unsigned long long* __restrict__ bits) {
    size_t gid = (size_t)blockIdx.x * 256 + threadIdx.x;
    float v = adj[gid];
    unsigned long long m = __ballot(v > 0.f);
    if ((threadIdx.x & 63) == 0) bits[gid >> 6] = m;
}

// ======== B-fragment layout: frag id = nt32*(K/16)+kt, 1 KB each ========
__device__ inline void wfrag_kn_body(
        const float* __restrict__ W, unsigned short* __restrict__ out,
        int K, int N, int fblk, int t) {
    int f = fblk * 4 + (t >> 6);
    int slot = t & 63, kh = slot >> 5, lm = slot & 31;
    int nfk = K >> 4;
    int nt = f / nfk, kt = f - nt * nfk;
    const float* wp = W + (size_t)(kt * 16 + kh * 8) * N + nt * 32 + lm;
    ushort4_t o0, o1;
    o0.x = f2bf(wp[0]);             o0.y = f2bf(wp[(size_t)N]);
    o0.z = f2bf(wp[2 * (size_t)N]); o0.w = f2bf(wp[3 * (size_t)N]);
    o1.x = f2bf(wp[4 * (size_t)N]); o1.y = f2bf(wp[5 * (size_t)N]);
    o1.z = f2bf(wp[6 * (size_t)N]); o1.w = f2bf(wp[7 * (size_t)N]);
    unsigned short* op = out + (size_t)f * 512 + slot * 8;
    *(ushort4_t*)op = o0;
    *(ushort4_t*)(op + 4) = o1;
}

__device__ inline void wfrag_nk_body(
        const float* __restrict__ W, unsigned short* __restrict__ out,
        int K, int fblk, int t) {
    int f = fblk * 4 + (t >> 6);
    int slot = t & 63, kh = slot >> 5, lm = slot & 31;
    int nfk = K >> 4;
    int nt = f / nfk, kt = f - nt * nfk;
    const float* wp = W + (size_t)(nt * 32 + lm) * K + kt * 16 + kh * 8;
    float4 a = *(const float4*)wp, b = *(const float4*)(wp + 4);
    ushort4_t o0, o1;
    o0.x = f2bf(a.x); o0.y = f2bf(a.y); o0.z = f2bf(a.z); o0.w = f2bf(a.w);
    o1.x = f2bf(b.x); o1.y = f2bf(b.y); o1.z = f2bf(b.z); o1.w = f2bf(b.w);
    unsigned short* op = out + (size_t)f * 512 + slot * 8;
    *(ushort4_t*)op = o0;
    *(ushort4_t*)(op + 4) = o1;
}

// ---------------- merged prep: x cast + all weight frag tables (1 launch) ----------------
// grid 4384: [0,3072) x-cast | [3072,3840) WhF | [3840,4096) WoF | [4096,4352) WlF | [4352,4384) WnF
__global__ __launch_bounds__(256) void prep_misc_kernel(
        const float* __restrict__ x, unsigned short* __restrict__ x_bf,
        const float* __restrict__ W_heads, unsigned short* __restrict__ WhF,
        const float* __restrict__ W_out,   unsigned short* __restrict__ WoF,
        const float* __restrict__ W_lin,   unsigned short* __restrict__ WlF,
        const float* __restrict__ W_ln,    unsigned short* __restrict__ WnF) {
    int blk = blockIdx.x, t = threadIdx.x;
    if (blk < 3072) {
        size_t i = (size_t)blk * 256 + t;
        float4 v = ((const float4*)x)[i];
        ushort4_t o;
        o.x = f2bf(v.x); o.y = f2bf(v.y); o.z = f2bf(v.z); o.w = f2bf(v.w);
        ((ushort4_t*)x_bf)[i] = o;
    } else if (blk < 3840) {
        int idx = blk - 3072;
        int head = idx / 96, fblk = idx - head * 96;
        wfrag_kn_body(W_heads + (size_t)head * Ff * Oo, WhF + (size_t)head * 384 * 512,
                      Ff, Oo, fblk, t);
    } else if (blk < 4096) {
        wfrag_kn_body(W_out, WoF, Hh * Oo, Oo, blk - 3840, t);
    } else if (blk < 4352) {
        wfrag_nk_body(W_lin, WlF, Hh * Oo, blk - 4096, t);
    } else {
        wfrag_nk_body(W_ln, WnF, Oo, blk - 4352, t);
    }
}

// ---------------- 32-row-tile MFMA GEMM, BK=64 (R16 verified) ----------------
template<int SWAPZ>
__global__ __launch_bounds__(256) void gemm32_kernel(
        const unsigned short* __restrict__ A, int K, long long sA, int bAshift,
        const unsigned short* __restrict__ BF, long long sB, int bmask,
        float* __restrict__ C, long long sC,
        unsigned short* __restrict__ CF, long long sCF, int Mtot,
        const float* __restrict__ bias, int mode,
        const float* __restrict__ aall, int amask,
        float* __restrict__ E1p, float* __restrict__ E1n, float2* __restrict__ E2pn) {
    int z  = SWAPZ ? blockIdx.x : blockIdx.z;
    int mx = SWAPZ ? blockIdx.y : blockIdx.x;
    A  += (size_t)(z >> bAshift) * sA;
    BF += (size_t)(z & bmask) * sB;
    if (C) C += (size_t)z * sC;
    if (CF) CF += (size_t)z * sCF;
    int m0 = mx * 32;
    int t = threadIdx.x;
    int wv = t >> 6, lane = t & 63;
    int lm = lane & 31, kh = lane >> 5;
    int nfk = K >> 4;
    __shared__ __align__(16) unsigned short As[32][72];
    f32x16 acc[2] = {};
    int sr = t >> 3, sc2 = (t & 7) * 8;
    const unsigned short* ag  = A + (size_t)(m0 + sr) * K + sc2;
    const unsigned short* bg0 = BF + (size_t)(wv * 2) * nfk * 512;
    const unsigned short* bg1 = bg0 + (size_t)nfk * 512;
    for (int k0 = 0; k0 < K; k0 += 64) {
        *(short8*)&As[sr][sc2] = *(const short8*)(ag + k0);
        int kt0 = k0 >> 4;
        __syncthreads();
#pragma unroll
        for (int s = 0; s < 4; ++s) {
            short8 a0 = *(const short8*)&As[lm][s * 16 + kh * 8];
            short8 b0 = *(const short8*)(bg0 + (size_t)(kt0 + s) * 512 + lane * 8);
            short8 b1 = *(const short8*)(bg1 + (size_t)(kt0 + s) * 512 + lane * 8);
            acc[0] = __builtin_amdgcn_mfma_f32_32x32x16_bf16(a0, b0, acc[0], 0, 0, 0);
            acc[1] = __builtin_amdgcn_mfma_f32_32x32x16_bf16(a0, b1, acc[1], 0, 0, 0);
        }
        __syncthreads();
    }
#pragma unroll
    for (int nt = 0; nt < 2; ++nt) {
        int colg = wv * 64 + nt * 32 + lm;
        float bv = (mode == 2) ? bias[colg] : 0.f;
        if (C) {
#pragma unroll
            for (int reg = 0; reg < 16; ++reg) {
                int rl = 4 * kh + (reg & 3) + 8 * (reg >> 2);
                float v = acc[nt][reg];
                if (mode == 2) { v += bv; v = fmaxf(v, 0.f); }
                C[(size_t)(m0 + rl) * 256 + colg] = v;
            }
        }
        if (mode == 1) {
#pragma unroll
            for (int q = 0; q < 4; ++q) {
                int kt = m0 / 16 + (q >> 1);
                size_t fi = ((size_t)(colg >> 5) * (Mtot / 16) + kt) * 512 +
                            ((q & 1) * 32 + (colg & 31)) * 8 + kh * 4;
                ushort4_t pk;
                pk.x = f2bf(acc[nt][q * 4 + 0]);
                pk.y = f2bf(acc[nt][q * 4 + 1]);
                pk.z = f2bf(acc[nt][q * 4 + 2]);
                pk.w = f2bf(acc[nt][q * 4 + 3]);
                *(ushort4_t*)(CF + fi) = pk;
            }
        }
    }
    if (aall) {
        const float* av = aall + (size_t)(z & amask) * 512;
        float a1v0 = av[wv * 64 + lm],       a1v1 = av[wv * 64 + 32 + lm];
        float a2v0 = av[256 + wv * 64 + lm], a2v1 = av[256 + wv * 64 + 32 + lm];
        float* sbuf = (float*)As;
#pragma unroll
        for (int reg = 0; reg < 16; ++reg) {
            int rl = 4 * kh + (reg & 3) + 8 * (reg >> 2);
            float v1 = acc[0][reg] * a1v0 + acc[1][reg] * a1v1;
            float v2 = acc[0][reg] * a2v0 + acc[1][reg] * a2v1;
#pragma unroll
            for (int m = 1; m <= 16; m <<= 1) {
                v1 += __shfl_xor(v1, m, 64);
                v2 += __shfl_xor(v2, m, 64);
            }
            if (lm == 0) { sbuf[rl * 8 + wv] = v1; sbuf[rl * 8 + 4 + wv] = v2; }
        }
        __syncthreads();
        if (t < 32) {
            float s1 = sbuf[t * 8] + sbuf[t * 8 + 1] + sbuf[t * 8 + 2] + sbuf[t * 8 + 3];
            float s2 = sbuf[t * 8 + 4] + sbuf[t * 8 + 5] + sbuf[t * 8 + 6] + sbuf[t * 8 + 7];
            size_t ei = (size_t)z * Nn + m0 + t;
            E1p[ei] = __expf(s1);
            E1n[ei] = __expf(0.2f * s1);
            E2pn[ei] = make_float2(__expf(s2), __expf(0.2f * s2));
        }
    }
}

// ---------------- 32-row dual GEMM (R16 verified) ----------------
__global__ __launch_bounds__(256) void gemm32_dual_kernel(
        const unsigned short* __restrict__ A, int K, long long sA,
        const unsigned short* __restrict__ BF,
        unsigned short* __restrict__ h2f, float* __restrict__ lin,
        const float* __restrict__ a_out,
        float* __restrict__ E1p, float* __restrict__ E1n, float2* __restrict__ E2pn) {
    int b = blockIdx.z, ng = blockIdx.y;
    A += (size_t)b * sA;
    int nfk = K >> 4;
    BF += (size_t)ng * 8 * nfk * 512;
    int m0 = blockIdx.x * 32;
    int t = threadIdx.x;
    int wv = t >> 6, lane = t & 63;
    int lm = lane & 31, kh = lane >> 5;
    __shared__ __align__(16) unsigned short As[32][72];
    f32x16 acc[2] = {};
    int sr = t >> 3, sc2 = (t & 7) * 8;
    const unsigned short* ag  = A + (size_t)(m0 + sr) * K + sc2;
    const unsigned short* bg0 = BF + (size_t)(wv * 2) * nfk * 512;
    const unsigned short* bg1 = bg0 + (size_t)nfk * 512;
    for (int k0 = 0; k0 < K; k0 += 64) {
        *(short8*)&As[sr][sc2] = *(const short8*)(ag + k0);
        int kt0 = k0 >> 4;
        __syncthreads();
#pragma unroll
        for (int s = 0; s < 4; ++s) {
            short8 a0 = *(const short8*)&As[lm][s * 16 + kh * 8];
            short8 b0 = *(const short8*)(bg0 + (size_t)(kt0 + s) * 512 + lane * 8);
            short8 b1 = *(const short8*)(bg1 + (size_t)(kt0 + s) * 512 + lane * 8);
            acc[0] = __builtin_amdgcn_mfma_f32_32x32x16_bf16(a0, b0, acc[0], 0, 0, 0);
            acc[1] = __builtin_amdgcn_mfma_f32_32x32x16_bf16(a0, b1, acc[1], 0, 0, 0);
        }
        __syncthreads();
    }
    if (ng == 1) {
        float* C = lin + (size_t)b * Nn * 256;
#pragma unroll
        for (int nt = 0; nt < 2; ++nt) {
            int colg = wv * 64 + nt * 32 + lm;
#pragma unroll
            for (int reg = 0; reg < 16; ++reg) {
                int rl = 4 * kh + (reg & 3) + 8 * (reg >> 2);
                C[(size_t)(m0 + rl) * 256 + colg] = acc[nt][reg];
            }
        }
    } else {
        unsigned short* CF = h2f + (size_t)b * 524288;
#pragma unroll
        for (int nt = 0; nt < 2; ++nt) {
            int colg = wv * 64 + nt * 32 + lm;
#pragma unroll
            for (int q = 0; q < 4; ++q) {
                int kt = m0 / 16 + (q >> 1);
                size_t fi = ((size_t)(colg >> 5) * 128 + kt) * 512 +
                            ((q & 1) * 32 + (colg & 31)) * 8 + kh * 4;
                ushort4_t pk;
                pk.x = f2bf(acc[nt][q * 4 + 0]);
                pk.y = f2bf(acc[nt][q * 4 + 1]);
                pk.z = f2bf(acc[nt][q * 4 + 2]);
                pk.w = f2bf(acc[nt][q * 4 + 3]);
                *(ushort4_t*)(CF + fi) = pk;
            }
        }
        float a1v0 = a_out[wv * 64 + lm],       a1v1 = a_out[wv * 64 + 32 + lm];
        float a2v0 = a_out[256 + wv * 64 + lm], a2v1 = a_out[256 + wv * 64 + 32 + lm];
        float* sbuf = (float*)As;
#pragma unroll
        for (int reg = 0; reg < 16; ++reg) {
            int rl = 4 * kh + (reg & 3) + 8 * (reg >> 2);
            float v1 = acc[0][reg] * a1v0 + acc[1][reg] * a1v1;
            float v2 = acc[0][reg] * a2v0 + acc[1][reg] * a2v1;
#pragma unroll
            for (int m = 1; m <= 16; m <<= 1) {
                v1 += __shfl_xor(v1, m, 64);
                v2 += __shfl_xor(v2, m, 64);
            }
            if (lm == 0) { sbuf[rl * 8 + wv] = v1; sbuf[rl * 8 + 4 + wv] = v2; }
        }
        __syncthreads();
        if (t < 32) {
            float s1 = sbuf[t * 8] + sbuf[t * 8 + 1] + sbuf[t * 8 + 2] + sbuf[t * 8 + 3];
            float s2 = sbuf[t * 8 + 4] + sbuf[t * 8 + 5] + sbuf[t * 8 + 6] + sbuf[t * 8 + 7];
            size_t ei = (size_t)b * Nn + m0 + t;
            E1p[ei] = __expf(s1);
            E1n[ei] = __expf(0.2f * s1);
            E2pn[ei] = make_float2(__expf(s2), __expf(0.2f * s2));
        }
    }
}

// ---------------- final GEMM with fused combine: out = relu((Σpacc/Σl + lin + b_lin) @ WnF + b_ln) ----------------
__global__ __launch_bounds__(256) void gemm32_final_kernel(
        const float* __restrict__ pacc, const float* __restrict__ plsum,
        const float* __restrict__ lin, const float* __restrict__ b_lin,
        const unsigned short* __restrict__ BF, const float* __restrict__ b_ln,
        float* __restrict__ out) {
    int b = blockIdx.z;
    int m0 = blockIdx.x * 32;
    int t = threadIdx.x;
    int wv = t >> 6, lane = t & 63;
    int lm = lane & 31, kh = lane >> 5;
    constexpr int nfk = 16;   // K = 256
    __shared__ __align__(16) unsigned short As[32][72];
    f32x16 acc[2] = {};
    int sr = t >> 3, sc2 = (t & 7) * 8;
    int row = m0 + sr;
    int BN = Bb * Nn;
    size_t prow = (size_t)b * Nn + row;
    float li = 1.f / (plsum[prow] + plsum[prow + BN] + plsum[prow + 2 * BN] + plsum[prow + 3 * BN]);
    size_t ps4 = (size_t)Bb * Nn * 256;
    const unsigned short* bg0 = BF + (size_t)(wv * 2) * nfk * 512;
    const unsigned short* bg1 = bg0 + (size_t)nfk * 512;
    for (int k0 = 0; k0 < 256; k0 += 64) {
        int o = k0 + sc2;
        size_t pidx = prow * 256 + o;
        float4 sA = *(const float4*)(pacc + pidx);
        float4 sB = *(const float4*)(pacc + pidx + 4);
#pragma unroll
        for (int k = 1; k < 4; ++k) {
            float4 qA = *(const float4*)(pacc + k * ps4 + pidx);
            float4 qB = *(const float4*)(pacc + k * ps4 + pidx + 4);
            sA.x += qA.x; sA.y += qA.y; sA.z += qA.z; sA.w += qA.w;
            sB.x += qB.x; sB.y += qB.y; sB.z += qB.z; sB.w += qB.w;
        }
        float4 lvA = *(const float4*)(lin + pidx);
        float4 lvB = *(const float4*)(lin + pidx + 4);
        float4 bvA = *(const float4*)(b_lin + o);
        float4 bvB = *(const float4*)(b_lin + o + 4);
        ushort4_t p0, p1;
        p0.x = f2bf(sA.x * li + lvA.x + bvA.x);
        p0.y = f2bf(sA.y * li + lvA.y + bvA.y);
        p0.z = f2bf(sA.z * li + lvA.z + bvA.z);
        p0.w = f2bf(sA.w * li + lvA.w + bvA.w);
        p1.x = f2bf(sB.x * li + lvB.x + bvB.x);
        p1.y = f2bf(sB.y * li + lvB.y + bvB.y);
        p1.z = f2bf(sB.z * li + lvB.z + bvB.z);
        p1.w = f2bf(sB.w * li + lvB.w + bvB.w);
        int kt0 = k0 >> 4;
        *(ushort4_t*)&As[sr][sc2]     = p0;
        *(ushort4_t*)&As[sr][sc2 + 4] = p1;
        __syncthreads();
#pragma unroll
        for (int s = 0; s < 4; ++s) {
            short8 a0 = *(const short8*)&As[lm][s * 16 + kh * 8];
            short8 b0 = *(const short8*)(bg0 + (size_t)(kt0 + s) * 512 + lane * 8);
            short8 b1 = *(const short8*)(bg1 + (size_t)(kt0 + s) * 512 + lane * 8);
            acc[0] = __builtin_amdgcn_mfma_f32_32x32x16_bf16(a0, b0, acc[0], 0, 0, 0);
            acc[1] = __builtin_amdgcn_mfma_f32_32x32x16_bf16(a0, b1, acc[1], 0, 0, 0);
        }
        __syncthreads();
    }
    float* C = out + (size_t)b * Nn * 256;
#pragma unroll
    for (int nt = 0; nt < 2; ++nt) {
        int colg = wv * 64 + nt * 32 + lm;
        float bv = b_ln[colg];
#pragma unroll
        for (int reg = 0; reg < 16; ++reg) {
            int rl = 4 * kh + (reg & 3) + 8 * (reg >> 2);
            float v = fmaxf(acc[nt][reg] + bv, 0.f);
            C[(size_t)(m0 + rl) * 256 + colg] = v;
        }
    }
}

// ---------------- attention v8: 32 i-rows/block, frag B (R15/R16 verified) ----------------
template<int JLEN, int MODE, int SWAPXY>
__global__ __launch_bounds__(256, 4) void attn_v8_kernel(
        const unsigned short* __restrict__ hfrag,
        const unsigned* __restrict__ bits,
        const float* __restrict__ E1p, const float* __restrict__ E1n,
        const float2* __restrict__ E2pn,
        unsigned short* __restrict__ outbf, int ldo,
        float* __restrict__ pacc, float* __restrict__ plsum,
        int hshift) {
    constexpr int W = JLEN / 32, NC = JLEN / 64, ABS = W + 1;
    int it = SWAPXY ? blockIdx.y : blockIdx.x;
    int bh = SWAPXY ? blockIdx.x : blockIdx.y;
    int js = blockIdx.z;
    int b = bh >> hshift, hd = bh & ((1 << hshift) - 1);
    int i0 = it * 32, jbase = js * JLEN;
    int kt0 = js * (JLEN / 16);
    int t = threadIdx.x, lane = t & 63;
    int wv = t >> 6, lm = lane & 31, kh = lane >> 5;
    int ti = t & 31, jq = t >> 5;

    __shared__ unsigned ab[32 * ABS];
    __shared__ __align__(16) unsigned short ps[2][32][64];
    __shared__ float lred[32][9];
    __shared__ float linv[32];

    const unsigned* bb = bits + ((size_t)b * Nn + i0) * 64 + (jbase >> 5);
    for (int k = t; k < 32 * W; k += 256) {
        int r = k / W, w0 = k - r * W;
        ab[r * ABS + w0] = bb[(size_t)r * 64 + w0];
    }
    __syncthreads();   // ab[] must be visible before computeP

    float e1p = E1p[(size_t)bh * Nn + i0 + ti];
    float e1n = E1n[(size_t)bh * Nn + i0 + ti];
    const float4* e2base = (const float4*)(E2pn + (size_t)bh * Nn + jbase);

    const unsigned short* bg0 = hfrag + (size_t)bh * 524288 + (size_t)(wv * 2) * 128 * 512;
    const unsigned short* bg1 = bg0 + 128 * 512;

    f32x16 acc[2] = {};
    float lp0 = 0.f, lp1 = 0.f;
    short8 Bpp[2][2];

    auto loadBs = [&](int c, int s, int slot) {
        int kt = kt0 + c * 4 + s;
        Bpp[slot][0] = *(const short8*)(bg0 + (size_t)kt * 512 + lane * 8);
        Bpp[slot][1] = *(const short8*)(bg1 + (size_t)kt * 512 + lane * 8);
    };
    auto computeP = [&](int c, int buf) {
        int cj = c * 64;
        unsigned word = ab[ti * ABS + (cj >> 5) + (jq >> 2)];
        unsigned field = (word >> ((jq & 3) * 8)) & 0xffu;
        const float4* ep = e2base + ((cj + jq * 8) >> 1);
        unsigned pk[4];
#pragma unroll
        for (int u = 0; u < 4; ++u) {
            float4 q = ep[u];
            float p0 = fmaxf(e1p * q.x, e1n * q.y);   // select==max (exact)
            p0 = ((field >> (2 * u)) & 1u) ? p0 : 0.f;
            float p1 = fmaxf(e1p * q.z, e1n * q.w);
            p1 = ((field >> (2 * u + 1)) & 1u) ? p1 : 0.f;
            if (u & 1) lp1 += p0 + p1; else lp0 += p0 + p1;
            __hip_bfloat162 hv = __float22bfloat162_rn(make_float2(p0, p1));
            pk[u] = *(unsigned*)&hv;
        }
        uint4 v; v.x = pk[0]; v.y = pk[1]; v.z = pk[2]; v.w = pk[3];
        *(uint4*)&ps[buf][ti][(jq ^ (ti & 7)) * 8] = v;
    };
    auto mfmaS = [&](int buf, int s, int slot) {
        int g = 2 * s + kh;
        short8 a0 = *(const short8*)&ps[buf][lm][(g ^ (lm & 7)) * 8];
        acc[0] = __builtin_amdgcn_mfma_f32_32x32x16_bf16(a0, Bpp[slot][0], acc[0], 0, 0, 0);
        acc[1] = __builtin_amdgcn_mfma_f32_32x32x16_bf16(a0, Bpp[slot][1], acc[1], 0, 0, 0);
    };

    computeP(0, 0);
    loadBs(0, 0, 0);
    __syncthreads();
    for (int c = 0; c < NC; ++c) {
        int cb = c & 1, nb = cb ^ 1;
        if (c + 1 < NC) computeP(c + 1, nb);
        loadBs(c, 1, 1);            mfmaS(cb, 0, 0);
        loadBs(c, 2, 0);            mfmaS(cb, 1, 1);
        loadBs(c, 3, 1);            mfmaS(cb, 2, 0);
        if (c + 1 < NC) loadBs(c + 1, 0, 0);
        mfmaS(cb, 3, 1);
        __syncthreads();
    }

    lred[ti][jq] = lp0 + lp1;
    __syncthreads();
    if (MODE == 0) {
        if (t < 32) {
            float s = 0.f;
#pragma unroll
            for (int k = 0; k < 8; ++k) s += lred[t][k];
            linv[t] = 1.f / s;
        }
        __syncthreads();
#pragma unroll
        for (int nt = 0; nt < 2; ++nt) {
            int o = wv * 64 + nt * 32 + lm;
#pragma unroll
            for (int reg = 0; reg < 16; ++reg) {
                int rl = 4 * kh + (reg & 3) + 8 * (reg >> 2);
                float v = acc[nt][reg] * linv[rl];
                v = v > 0.f ? v : expm1f(v);   // elu (layer 1)
                outbf[((size_t)b * Nn + i0 + rl) * ldo + (size_t)hd * Oo + o] = f2bf(v);
            }
        }
    } else {
        if (t < 32) {
            float s = 0.f;
#pragma unroll
            for (int k = 0; k < 8; ++k) s += lred[t][k];
            plsum[((size_t)js * Bb + b) * Nn + i0 + t] = s;
        }
        float* pa = pacc + (((size_t)js * Bb + b) * Nn) * 256;
#pragma unroll
        for (int nt = 0; nt < 2; ++nt) {
            int o = wv * 64 + nt * 32 + lm;
#pragma unroll
            for (int reg = 0; reg < 16; ++reg) {
                int rl = 4 * kh + (reg & 3) + 8 * (reg >> 2);
                pa[(size_t)(i0 + rl) * 256 + o] = acc[nt][reg];
            }
        }
    }
}

extern "C" void kernel_launch(void* const* d_in, const int* in_sizes, int n_in,
                              void* d_out, int out_size, void* d_ws, size_t ws_size,
                              hipStream_t stream) {
    const float* x       = (const float*)d_in[0];
    const float* adj     = (const float*)d_in[1];
    const float* W_heads = (const float*)d_in[3];
    const float* a_heads = (const float*)d_in[4];
    const float* W_out   = (const float*)d_in[5];
    const float* a_out   = (const float*)d_in[6];
    const float* W_lin   = (const float*)d_in[7];
    const float* b_lin   = (const float*)d_in[8];
    const float* W_ln    = (const float*)d_in[9];
    const float* b_ln    = (const float*)d_in[10];

    char* w = (char*)d_ws;
    float* pacc     = (float*)(w);                    // 4x4 MB (sh partials)
    float* lin      = (float*)(w + 33554432);
    float* E1p_mh   = (float*)(w + 41943040);
    float* E1n_mh   = (float*)(w + 42074112);
    float2* E2pn_mh = (float2*)(w + 42205184);
    float* E1p_sh   = (float*)(w + 42467328);
    float* E1n_sh   = (float*)(w + 42483712);
    float2* E2pn_sh = (float2*)(w + 42500096);
    unsigned long long* bits = (unsigned long long*)(w + 42532864);
    unsigned short* x_bf  = (unsigned short*)(w + 43581440);
    unsigned short* WhF   = (unsigned short*)(w + 49872896);
    unsigned short* WoF   = (unsigned short*)(w + 53018624);
    unsigned short* WlF   = (unsigned short*)(w + 54067200);
    unsigned short* WnF   = (unsigned short*)(w + 55115776);
    unsigned short* hfrag = (unsigned short*)(w + 55246848);   // 16 MB
    unsigned short* h2frag= (unsigned short*)(w + 72024064);   // 2 MB
    unsigned short* x1_bf = (unsigned short*)(w + 74121216);
    float* plsum = E1p_mh;

    // 0) prep: adjacency bitmask + merged cast/frag prep (2 launches)
    adjbits_kernel<<<(Bb * Nn * Nn) / 256, 256, 0, stream>>>(adj, bits);
    prep_misc_kernel<<<4384, 256, 0, stream>>>(
        x, x_bf, W_heads, WhF, W_out, WoF, W_lin, WlF, W_ln, WnF);

    // 1) h = x @ W_heads -> hfrag + fused mh scores/exp (z-major: XCD = z%8)
    gemm32_kernel<1><<<dim3(Bb * Hh, Nn / 32, 1), 256, 0, stream>>>(
        x_bf, Ff, (long long)Nn * Ff, 3, WhF, 384LL * 512, 7,
        nullptr, 0, hfrag, 524288, Nn, nullptr, 1,
        a_heads, 7, E1p_mh, E1n_mh, E2pn_mh);
    // 2) multihead attention + elu -> x1_bf  (32-row tiles, XCD = bh%8)
    attn_v8_kernel<2048, 0, 1><<<dim3(Bb * Hh, Nn / 32, 1), 256, 0, stream>>>(
        hfrag, (const unsigned*)bits, E1p_mh, E1n_mh, E2pn_mh,
        x1_bf, Hh * Oo, nullptr, nullptr, 3);
    // 3) fused dual GEMM: h2frag (+sh scores) and lin
    gemm32_dual_kernel<<<dim3(Nn / 32, 2, Bb), 256, 0, stream>>>(
        x1_bf, Hh * Oo, (long long)Nn * Hh * Oo, WoF, h2frag, lin,
        a_out, E1p_sh, E1n_sh, E2pn_sh);
    // 4) single-head attention, 4-way j-split partials
    attn_v8_kernel<512, 1, 0><<<dim3(Nn / 32, Bb, 4), 256, 0, stream>>>(
        h2frag, (const unsigned*)bits, E1p_sh, E1n_sh, E2pn_sh,
        nullptr, 0, pacc, plsum, 0);
    // 5) final GEMM with fused combine -> d_out
    gemm32_final_kernel<<<dim3(Nn / 32, 1, Bb), 256, 0, stream>>>(
        pacc, plsum, lin, b_lin, WnF, b_ln, (float*)d_out);
}

// Round 18
// 264.066 us; speedup vs baseline: 1.1202x; 1.0352x over previous
//
#include <hip/hip_runtime.h>
#include <hip/hip_bf16.h>

constexpr int Bb = 2, Nn = 2048, Ff = 768, Hh = 8, Oo = 256;

typedef __attribute__((ext_vector_type(8)))  short   short8;
typedef __attribute__((ext_vector_type(16))) float   f32x16;
typedef __attribute__((ext_vector_type(4)))  unsigned short ushort4_t;

__device__ inline unsigned short f2bf(float f) {
    unsigned u = __float_as_uint(f);
    u = (u + 0x7FFFu + ((u >> 16) & 1u)) >> 16;   // RNE
    return (unsigned short)u;
}

// ======== B-fragment layout: frag id = nt32*(K/16)+kt, 1 KB each ========
__device__ inline void wfrag_kn_body(
        const float* __restrict__ W, unsigned short* __restrict__ out,
        int K, int N, int fblk, int t) {
    int f = fblk * 4 + (t >> 6);
    int slot = t & 63, kh = slot >> 5, lm = slot & 31;
    int nfk = K >> 4;
    int nt = f / nfk, kt = f - nt * nfk;
    const float* wp = W + (size_t)(kt * 16 + kh * 8) * N + nt * 32 + lm;
    ushort4_t o0, o1;
    o0.x = f2bf(wp[0]);             o0.y = f2bf(wp[(size_t)N]);
    o0.z = f2bf(wp[2 * (size_t)N]); o0.w = f2bf(wp[3 * (size_t)N]);
    o1.x = f2bf(wp[4 * (size_t)N]); o1.y = f2bf(wp[5 * (size_t)N]);
    o1.z = f2bf(wp[6 * (size_t)N]); o1.w = f2bf(wp[7 * (size_t)N]);
    unsigned short* op = out + (size_t)f * 512 + slot * 8;
    *(ushort4_t*)op = o0;
    *(ushort4_t*)(op + 4) = o1;
}

__device__ inline void wfrag_nk_body(
        const float* __restrict__ W, unsigned short* __restrict__ out,
        int K, int fblk, int t) {
    int f = fblk * 4 + (t >> 6);
    int slot = t & 63, kh = slot >> 5, lm = slot & 31;
    int nfk = K >> 4;
    int nt = f / nfk, kt = f - nt * nfk;
    const float* wp = W + (size_t)(nt * 32 + lm) * K + kt * 16 + kh * 8;
    float4 a = *(const float4*)wp, b = *(const float4*)(wp + 4);
    ushort4_t o0, o1;
    o0.x = f2bf(a.x); o0.y = f2bf(a.y); o0.z = f2bf(a.z); o0.w = f2bf(a.w);
    o1.x = f2bf(b.x); o1.y = f2bf(b.y); o1.z = f2bf(b.z); o1.w = f2bf(b.w);
    unsigned short* op = out + (size_t)f * 512 + slot * 8;
    *(ushort4_t*)op = o0;
    *(ushort4_t*)(op + 4) = o1;
}

// ---------------- merged prep: adjbits + x cast + all weight frag tables (1 launch) ----------------
// grid 37152: [0,32768) adjbits | [32768,35840) x-cast | then WhF/WoF/WlF/WnF
__global__ __launch_bounds__(256) void prep_misc_kernel(
        const float* __restrict__ adj, unsigned long long* __restrict__ bits,
        const float* __restrict__ x, unsigned short* __restrict__ x_bf,
        const float* __restrict__ W_heads, unsigned short* __restrict__ WhF,
        const float* __restrict__ W_out,   unsigned short* __restrict__ WoF,
        const float* __restrict__ W_lin,   unsigned short* __restrict__ WlF,
        const float* __restrict__ W_ln,    unsigned short* __restrict__ WnF) {
    int blk = blockIdx.x, t = threadIdx.x;
    if (blk < 32768) {
        size_t gid = (size_t)blk * 256 + t;
        float v = adj[gid];
        unsigned long long m = __ballot(v > 0.f);
        if ((t & 63) == 0) bits[gid >> 6] = m;
    } else if (blk < 35840) {
        size_t i = (size_t)(blk - 32768) * 256 + t;
        float4 v = ((const float4*)x)[i];
        ushort4_t o;
        o.x = f2bf(v.x); o.y = f2bf(v.y); o.z = f2bf(v.z); o.w = f2bf(v.w);
        ((ushort4_t*)x_bf)[i] = o;
    } else if (blk < 36608) {
        int idx = blk - 35840;
        int head = idx / 96, fblk = idx - head * 96;
        wfrag_kn_body(W_heads + (size_t)head * Ff * Oo, WhF + (size_t)head * 384 * 512,
                      Ff, Oo, fblk, t);
    } else if (blk < 36864) {
        wfrag_kn_body(W_out, WoF, Hh * Oo, Oo, blk - 36608, t);
    } else if (blk < 37120) {
        wfrag_nk_body(W_lin, WlF, Hh * Oo, blk - 36864, t);
    } else {
        wfrag_nk_body(W_ln, WnF, Oo, blk - 37120, t);
    }
}

// ---------------- 32-row-tile MFMA GEMM, BK=128 ----------------
template<int SWAPZ>
__global__ __launch_bounds__(256) void gemm32_kernel(
        const unsigned short* __restrict__ A, int K, long long sA, int bAshift,
        const unsigned short* __restrict__ BF, long long sB, int bmask,
        float* __restrict__ C, long long sC,
        unsigned short* __restrict__ CF, long long sCF, int Mtot,
        const float* __restrict__ bias, int mode,
        const float* __restrict__ aall, int amask,
        float* __restrict__ E1p, float* __restrict__ E1n, float2* __restrict__ E2pn) {
    int z  = SWAPZ ? blockIdx.x : blockIdx.z;
    int mx = SWAPZ ? blockIdx.y : blockIdx.x;
    A  += (size_t)(z >> bAshift) * sA;
    BF += (size_t)(z & bmask) * sB;
    if (C) C += (size_t)z * sC;
    if (CF) CF += (size_t)z * sCF;
    int m0 = mx * 32;
    int t = threadIdx.x;
    int wv = t >> 6, lane = t & 63;
    int lm = lane & 31, kh = lane >> 5;
    int nfk = K >> 4;
    __shared__ __align__(16) unsigned short As[32][136];
    f32x16 acc[2] = {};
    int sr = t >> 3, sc2 = (t & 7) * 16;
    const unsigned short* ag  = A + (size_t)(m0 + sr) * K + sc2;
    const unsigned short* bg0 = BF + (size_t)(wv * 2) * nfk * 512;
    const unsigned short* bg1 = bg0 + (size_t)nfk * 512;
    for (int k0 = 0; k0 < K; k0 += 128) {
        *(short8*)&As[sr][sc2]     = *(const short8*)(ag + k0);
        *(short8*)&As[sr][sc2 + 8] = *(const short8*)(ag + k0 + 8);
        int kt0 = k0 >> 4;
        __syncthreads();
#pragma unroll
        for (int s = 0; s < 8; ++s) {
            short8 a0 = *(const short8*)&As[lm][s * 16 + kh * 8];
            short8 b0 = *(const short8*)(bg0 + (size_t)(kt0 + s) * 512 + lane * 8);
            short8 b1 = *(const short8*)(bg1 + (size_t)(kt0 + s) * 512 + lane * 8);
            acc[0] = __builtin_amdgcn_mfma_f32_32x32x16_bf16(a0, b0, acc[0], 0, 0, 0);
            acc[1] = __builtin_amdgcn_mfma_f32_32x32x16_bf16(a0, b1, acc[1], 0, 0, 0);
        }
        __syncthreads();
    }
#pragma unroll
    for (int nt = 0; nt < 2; ++nt) {
        int colg = wv * 64 + nt * 32 + lm;
        float bv = (mode == 2) ? bias[colg] : 0.f;
        if (C) {
#pragma unroll
            for (int reg = 0; reg < 16; ++reg) {
                int rl = 4 * kh + (reg & 3) + 8 * (reg >> 2);
                float v = acc[nt][reg];
                if (mode == 2) { v += bv; v = fmaxf(v, 0.f); }
                C[(size_t)(m0 + rl) * 256 + colg] = v;
            }
        }
        if (mode == 1) {
#pragma unroll
            for (int q = 0; q < 4; ++q) {
                int kt = m0 / 16 + (q >> 1);
                size_t fi = ((size_t)(colg >> 5) * (Mtot / 16) + kt) * 512 +
                            ((q & 1) * 32 + (colg & 31)) * 8 + kh * 4;
                ushort4_t pk;
                pk.x = f2bf(acc[nt][q * 4 + 0]);
                pk.y = f2bf(acc[nt][q * 4 + 1]);
                pk.z = f2bf(acc[nt][q * 4 + 2]);
                pk.w = f2bf(acc[nt][q * 4 + 3]);
                *(ushort4_t*)(CF + fi) = pk;
            }
        }
    }
    if (aall) {
        const float* av = aall + (size_t)(z & amask) * 512;
        float a1v0 = av[wv * 64 + lm],       a1v1 = av[wv * 64 + 32 + lm];
        float a2v0 = av[256 + wv * 64 + lm], a2v1 = av[256 + wv * 64 + 32 + lm];
        float* sbuf = (float*)As;
#pragma unroll
        for (int reg = 0; reg < 16; ++reg) {
            int rl = 4 * kh + (reg & 3) + 8 * (reg >> 2);
            float v1 = acc[0][reg] * a1v0 + acc[1][reg] * a1v1;
            float v2 = acc[0][reg] * a2v0 + acc[1][reg] * a2v1;
#pragma unroll
            for (int m = 1; m <= 16; m <<= 1) {
                v1 += __shfl_xor(v1, m, 64);
                v2 += __shfl_xor(v2, m, 64);
            }
            if (lm == 0) { sbuf[rl * 8 + wv] = v1; sbuf[rl * 8 + 4 + wv] = v2; }
        }
        __syncthreads();
        if (t < 32) {
            float s1 = sbuf[t * 8] + sbuf[t * 8 + 1] + sbuf[t * 8 + 2] + sbuf[t * 8 + 3];
            float s2 = sbuf[t * 8 + 4] + sbuf[t * 8 + 5] + sbuf[t * 8 + 6] + sbuf[t * 8 + 7];
            size_t ei = (size_t)z * Nn + m0 + t;
            E1p[ei] = __expf(s1);
            E1n[ei] = __expf(0.2f * s1);
            E2pn[ei] = make_float2(__expf(s2), __expf(0.2f * s2));
        }
    }
}

// ---------------- 32-row dual GEMM, BK=128: x1 @ [WoF ; WlF]; ng0 + fused sh scores ----------------
__global__ __launch_bounds__(256) void gemm32_dual_kernel(
        const unsigned short* __restrict__ A, int K, long long sA,
        const unsigned short* __restrict__ BF,
        unsigned short* __restrict__ h2f, float* __restrict__ lin,
        const float* __restrict__ a_out,
        float* __restrict__ E1p, float* __restrict__ E1n, float2* __restrict__ E2pn) {
    int b = blockIdx.z, ng = blockIdx.y;
    A += (size_t)b * sA;
    int nfk = K >> 4;
    BF += (size_t)ng * 8 * nfk * 512;
    int m0 = blockIdx.x * 32;
    int t = threadIdx.x;
    int wv = t >> 6, lane = t & 63;
    int lm = lane & 31, kh = lane >> 5;
    __shared__ __align__(16) unsigned short As[32][136];
    f32x16 acc[2] = {};
    int sr = t >> 3, sc2 = (t & 7) * 16;
    const unsigned short* ag  = A + (size_t)(m0 + sr) * K + sc2;
    const unsigned short* bg0 = BF + (size_t)(wv * 2) * nfk * 512;
    const unsigned short* bg1 = bg0 + (size_t)nfk * 512;
    for (int k0 = 0; k0 < K; k0 += 128) {
        *(short8*)&As[sr][sc2]     = *(const short8*)(ag + k0);
        *(short8*)&As[sr][sc2 + 8] = *(const short8*)(ag + k0 + 8);
        int kt0 = k0 >> 4;
        __syncthreads();
#pragma unroll
        for (int s = 0; s < 8; ++s) {
            short8 a0 = *(const short8*)&As[lm][s * 16 + kh * 8];
            short8 b0 = *(const short8*)(bg0 + (size_t)(kt0 + s) * 512 + lane * 8);
            short8 b1 = *(const short8*)(bg1 + (size_t)(kt0 + s) * 512 + lane * 8);
            acc[0] = __builtin_amdgcn_mfma_f32_32x32x16_bf16(a0, b0, acc[0], 0, 0, 0);
            acc[1] = __builtin_amdgcn_mfma_f32_32x32x16_bf16(a0, b1, acc[1], 0, 0, 0);
        }
        __syncthreads();
    }
    if (ng == 1) {
        float* C = lin + (size_t)b * Nn * 256;
#pragma unroll
        for (int nt = 0; nt < 2; ++nt) {
            int colg = wv * 64 + nt * 32 + lm;
#pragma unroll
            for (int reg = 0; reg < 16; ++reg) {
                int rl = 4 * kh + (reg & 3) + 8 * (reg >> 2);
                C[(size_t)(m0 + rl) * 256 + colg] = acc[nt][reg];
            }
        }
    } else {
        unsigned short* CF = h2f + (size_t)b * 524288;
#pragma unroll
        for (int nt = 0; nt < 2; ++nt) {
            int colg = wv * 64 + nt * 32 + lm;
#pragma unroll
            for (int q = 0; q < 4; ++q) {
                int kt = m0 / 16 + (q >> 1);
                size_t fi = ((size_t)(colg >> 5) * 128 + kt) * 512 +
                            ((q & 1) * 32 + (colg & 31)) * 8 + kh * 4;
                ushort4_t pk;
                pk.x = f2bf(acc[nt][q * 4 + 0]);
                pk.y = f2bf(acc[nt][q * 4 + 1]);
                pk.z = f2bf(acc[nt][q * 4 + 2]);
                pk.w = f2bf(acc[nt][q * 4 + 3]);
                *(ushort4_t*)(CF + fi) = pk;
            }
        }
        float a1v0 = a_out[wv * 64 + lm],       a1v1 = a_out[wv * 64 + 32 + lm];
        float a2v0 = a_out[256 + wv * 64 + lm], a2v1 = a_out[256 + wv * 64 + 32 + lm];
        float* sbuf = (float*)As;
#pragma unroll
        for (int reg = 0; reg < 16; ++reg) {
            int rl = 4 * kh + (reg & 3) + 8 * (reg >> 2);
            float v1 = acc[0][reg] * a1v0 + acc[1][reg] * a1v1;
            float v2 = acc[0][reg] * a2v0 + acc[1][reg] * a2v1;
#pragma unroll
            for (int m = 1; m <= 16; m <<= 1) {
                v1 += __shfl_xor(v1, m, 64);
                v2 += __shfl_xor(v2, m, 64);
            }
            if (lm == 0) { sbuf[rl * 8 + wv] = v1; sbuf[rl * 8 + 4 + wv] = v2; }
        }
        __syncthreads();
        if (t < 32) {
            float s1 = sbuf[t * 8] + sbuf[t * 8 + 1] + sbuf[t * 8 + 2] + sbuf[t * 8 + 3];
            float s2 = sbuf[t * 8 + 4] + sbuf[t * 8 + 5] + sbuf[t * 8 + 6] + sbuf[t * 8 + 7];
            size_t ei = (size_t)b * Nn + m0 + t;
            E1p[ei] = __expf(s1);
            E1n[ei] = __expf(0.2f * s1);
            E2pn[ei] = make_float2(__expf(s2), __expf(0.2f * s2));
        }
    }
}

// ---------------- final GEMM with fused combine (R17 verified) ----------------
__global__ __launch_bounds__(256) void gemm32_final_kernel(
        const float* __restrict__ pacc, const float* __restrict__ plsum,
        const float* __restrict__ lin, const float* __restrict__ b_lin,
        const unsigned short* __restrict__ BF, const float* __restrict__ b_ln,
        float* __restrict__ out) {
    int b = blockIdx.z;
    int m0 = blockIdx.x * 32;
    int t = threadIdx.x;
    int wv = t >> 6, lane = t & 63;
    int lm = lane & 31, kh = lane >> 5;
    constexpr int nfk = 16;   // K = 256
    __shared__ __align__(16) unsigned short As[32][72];
    f32x16 acc[2] = {};
    int sr = t >> 3, sc2 = (t & 7) * 8;
    int row = m0 + sr;
    int BN = Bb * Nn;
    size_t prow = (size_t)b * Nn + row;
    float li = 1.f / (plsum[prow] + plsum[prow + BN] + plsum[prow + 2 * BN] + plsum[prow + 3 * BN]);
    size_t ps4 = (size_t)Bb * Nn * 256;
    const unsigned short* bg0 = BF + (size_t)(wv * 2) * nfk * 512;
    const unsigned short* bg1 = bg0 + (size_t)nfk * 512;
    for (int k0 = 0; k0 < 256; k0 += 64) {
        int o = k0 + sc2;
        size_t pidx = prow * 256 + o;
        float4 sA = *(const float4*)(pacc + pidx);
        float4 sB = *(const float4*)(pacc + pidx + 4);
#pragma unroll
        for (int k = 1; k < 4; ++k) {
            float4 qA = *(const float4*)(pacc + k * ps4 + pidx);
            float4 qB = *(const float4*)(pacc + k * ps4 + pidx + 4);
            sA.x += qA.x; sA.y += qA.y; sA.z += qA.z; sA.w += qA.w;
            sB.x += qB.x; sB.y += qB.y; sB.z += qB.z; sB.w += qB.w;
        }
        float4 lvA = *(const float4*)(lin + pidx);
        float4 lvB = *(const float4*)(lin + pidx + 4);
        float4 bvA = *(const float4*)(b_lin + o);
        float4 bvB = *(const float4*)(b_lin + o + 4);
        ushort4_t p0, p1;
        p0.x = f2bf(sA.x * li + lvA.x + bvA.x);
        p0.y = f2bf(sA.y * li + lvA.y + bvA.y);
        p0.z = f2bf(sA.z * li + lvA.z + bvA.z);
        p0.w = f2bf(sA.w * li + lvA.w + bvA.w);
        p1.x = f2bf(sB.x * li + lvB.x + bvB.x);
        p1.y = f2bf(sB.y * li + lvB.y + bvB.y);
        p1.z = f2bf(sB.z * li + lvB.z + bvB.z);
        p1.w = f2bf(sB.w * li + lvB.w + bvB.w);
        int kt0 = k0 >> 4;
        *(ushort4_t*)&As[sr][sc2]     = p0;
        *(ushort4_t*)&As[sr][sc2 + 4] = p1;
        __syncthreads();
#pragma unroll
        for (int s = 0; s < 4; ++s) {
            short8 a0 = *(const short8*)&As[lm][s * 16 + kh * 8];
            short8 b0 = *(const short8*)(bg0 + (size_t)(kt0 + s) * 512 + lane * 8);
            short8 b1 = *(const short8*)(bg1 + (size_t)(kt0 + s) * 512 + lane * 8);
            acc[0] = __builtin_amdgcn_mfma_f32_32x32x16_bf16(a0, b0, acc[0], 0, 0, 0);
            acc[1] = __builtin_amdgcn_mfma_f32_32x32x16_bf16(a0, b1, acc[1], 0, 0, 0);
        }
        __syncthreads();
    }
    float* C = out + (size_t)b * Nn * 256;
#pragma unroll
    for (int nt = 0; nt < 2; ++nt) {
        int colg = wv * 64 + nt * 32 + lm;
        float bv = b_ln[colg];
#pragma unroll
        for (int reg = 0; reg < 16; ++reg) {
            int rl = 4 * kh + (reg & 3) + 8 * (reg >> 2);
            float v = fmaxf(acc[nt][reg] + bv, 0.f);
            C[(size_t)(m0 + rl) * 256 + colg] = v;
        }
    }
}

// ---------------- attention v8: 32 i-rows/block, frag B (R15-R17 verified) ----------------
template<int JLEN, int MODE, int SWAPXY>
__global__ __launch_bounds__(256, 4) void attn_v8_kernel(
        const unsigned short* __restrict__ hfrag,
        const unsigned* __restrict__ bits,
        const float* __restrict__ E1p, const float* __restrict__ E1n,
        const float2* __restrict__ E2pn,
        unsigned short* __restrict__ outbf, int ldo,
        float* __restrict__ pacc, float* __restrict__ plsum,
        int hshift) {
    constexpr int W = JLEN / 32, NC = JLEN / 64, ABS = W + 1;
    int it = SWAPXY ? blockIdx.y : blockIdx.x;
    int bh = SWAPXY ? blockIdx.x : blockIdx.y;
    int js = blockIdx.z;
    int b = bh >> hshift, hd = bh & ((1 << hshift) - 1);
    int i0 = it * 32, jbase = js * JLEN;
    int kt0 = js * (JLEN / 16);
    int t = threadIdx.x, lane = t & 63;
    int wv = t >> 6, lm = lane & 31, kh = lane >> 5;
    int ti = t & 31, jq = t >> 5;

    __shared__ unsigned ab[32 * ABS];
    __shared__ __align__(16) unsigned short ps[2][32][64];
    __shared__ float lred[32][9];
    __shared__ float linv[32];

    const unsigned* bb = bits + ((size_t)b * Nn + i0) * 64 + (jbase >> 5);
    for (int k = t; k < 32 * W; k += 256) {
        int r = k / W, w0 = k - r * W;
        ab[r * ABS + w0] = bb[(size_t)r * 64 + w0];
    }
    __syncthreads();   // ab[] must be visible before computeP

    float e1p = E1p[(size_t)bh * Nn + i0 + ti];
    float e1n = E1n[(size_t)bh * Nn + i0 + ti];
    const float4* e2base = (const float4*)(E2pn + (size_t)bh * Nn + jbase);

    const unsigned short* bg0 = hfrag + (size_t)bh * 524288 + (size_t)(wv * 2) * 128 * 512;
    const unsigned short* bg1 = bg0 + 128 * 512;

    f32x16 acc[2] = {};
    float lp0 = 0.f, lp1 = 0.f;
    short8 Bpp[2][2];

    auto loadBs = [&](int c, int s, int slot) {
        int kt = kt0 + c * 4 + s;
        Bpp[slot][0] = *(const short8*)(bg0 + (size_t)kt * 512 + lane * 8);
        Bpp[slot][1] = *(const short8*)(bg1 + (size_t)kt * 512 + lane * 8);
    };
    auto computeP = [&](int c, int buf) {
        int cj = c * 64;
        unsigned word = ab[ti * ABS + (cj >> 5) + (jq >> 2)];
        unsigned field = (word >> ((jq & 3) * 8)) & 0xffu;
        const float4* ep = e2base + ((cj + jq * 8) >> 1);
        unsigned pk[4];
#pragma unroll
        for (int u = 0; u < 4; ++u) {
            float4 q = ep[u];
            float p0 = fmaxf(e1p * q.x, e1n * q.y);   // select==max (exact)
            p0 = ((field >> (2 * u)) & 1u) ? p0 : 0.f;
            float p1 = fmaxf(e1p * q.z, e1n * q.w);
            p1 = ((field >> (2 * u + 1)) & 1u) ? p1 : 0.f;
            if (u & 1) lp1 += p0 + p1; else lp0 += p0 + p1;
            __hip_bfloat162 hv = __float22bfloat162_rn(make_float2(p0, p1));
            pk[u] = *(unsigned*)&hv;
        }
        uint4 v; v.x = pk[0]; v.y = pk[1]; v.z = pk[2]; v.w = pk[3];
        *(uint4*)&ps[buf][ti][(jq ^ (ti & 7)) * 8] = v;
    };
    auto mfmaS = [&](int buf, int s, int slot) {
        int g = 2 * s + kh;
        short8 a0 = *(const short8*)&ps[buf][lm][(g ^ (lm & 7)) * 8];
        acc[0] = __builtin_amdgcn_mfma_f32_32x32x16_bf16(a0, Bpp[slot][0], acc[0], 0, 0, 0);
        acc[1] = __builtin_amdgcn_mfma_f32_32x32x16_bf16(a0, Bpp[slot][1], acc[1], 0, 0, 0);
    };

    computeP(0, 0);
    loadBs(0, 0, 0);
    __syncthreads();
    for (int c = 0; c < NC; ++c) {
        int cb = c & 1, nb = cb ^ 1;
        if (c + 1 < NC) computeP(c + 1, nb);
        loadBs(c, 1, 1);            mfmaS(cb, 0, 0);
        loadBs(c, 2, 0);            mfmaS(cb, 1, 1);
        loadBs(c, 3, 1);            mfmaS(cb, 2, 0);
        if (c + 1 < NC) loadBs(c + 1, 0, 0);
        mfmaS(cb, 3, 1);
        __syncthreads();
    }

    lred[ti][jq] = lp0 + lp1;
    __syncthreads();
    if (MODE == 0) {
        if (t < 32) {
            float s = 0.f;
#pragma unroll
            for (int k = 0; k < 8; ++k) s += lred[t][k];
            linv[t] = 1.f / s;
        }
        __syncthreads();
#pragma unroll
        for (int nt = 0; nt < 2; ++nt) {
            int o = wv * 64 + nt * 32 + lm;
#pragma unroll
            for (int reg = 0; reg < 16; ++reg) {
                int rl = 4 * kh + (reg & 3) + 8 * (reg >> 2);
                float v = acc[nt][reg] * linv[rl];
                v = v > 0.f ? v : expm1f(v);   // elu (layer 1)
                outbf[((size_t)b * Nn + i0 + rl) * ldo + (size_t)hd * Oo + o] = f2bf(v);
            }
        }
    } else {
        if (t < 32) {
            float s = 0.f;
#pragma unroll
            for (int k = 0; k < 8; ++k) s += lred[t][k];
            plsum[((size_t)js * Bb + b) * Nn + i0 + t] = s;
        }
        float* pa = pacc + (((size_t)js * Bb + b) * Nn) * 256;
#pragma unroll
        for (int nt = 0; nt < 2; ++nt) {
            int o = wv * 64 + nt * 32 + lm;
#pragma unroll
            for (int reg = 0; reg < 16; ++reg) {
                int rl = 4 * kh + (reg & 3) + 8 * (reg >> 2);
                pa[(size_t)(i0 + rl) * 256 + o] = acc[nt][reg];
            }
        }
    }
}

extern "C" void kernel_launch(void* const* d_in, const int* in_sizes, int n_in,
                              void* d_out, int out_size, void* d_ws, size_t ws_size,
                              hipStream_t stream) {
    const float* x       = (const float*)d_in[0];
    const float* adj     = (const float*)d_in[1];
    const float* W_heads = (const float*)d_in[3];
    const float* a_heads = (const float*)d_in[4];
    const float* W_out   = (const float*)d_in[5];
    const float* a_out   = (const float*)d_in[6];
    const float* W_lin   = (const float*)d_in[7];
    const float* b_lin   = (const float*)d_in[8];
    const float* W_ln    = (const float*)d_in[9];
    const float* b_ln    = (const float*)d_in[10];

    char* w = (char*)d_ws;
    float* pacc     = (float*)(w);                    // 4x4 MB (sh partials)
    float* lin      = (float*)(w + 33554432);
    float* E1p_mh   = (float*)(w + 41943040);
    float* E1n_mh   = (float*)(w + 42074112);
    float2* E2pn_mh = (float2*)(w + 42205184);
    float* E1p_sh   = (float*)(w + 42467328);
    float* E1n_sh   = (float*)(w + 42483712);
    float2* E2pn_sh = (float2*)(w + 42500096);
    unsigned long long* bits = (unsigned long long*)(w + 42532864);
    unsigned short* x_bf  = (unsigned short*)(w + 43581440);
    unsigned short* WhF   = (unsigned short*)(w + 49872896);
    unsigned short* WoF   = (unsigned short*)(w + 53018624);
    unsigned short* WlF   = (unsigned short*)(w + 54067200);
    unsigned short* WnF   = (unsigned short*)(w + 55115776);
    unsigned short* hfrag = (unsigned short*)(w + 55246848);   // 16 MB
    unsigned short* h2frag= (unsigned short*)(w + 72024064);   // 2 MB
    unsigned short* x1_bf = (unsigned short*)(w + 74121216);
    float* plsum = E1p_mh;

    // 0) merged prep: adjbits + x cast + all weight frags (1 launch)
    prep_misc_kernel<<<37152, 256, 0, stream>>>(
        adj, bits, x, x_bf, W_heads, WhF, W_out, WoF, W_lin, WlF, W_ln, WnF);

    // 1) h = x @ W_heads -> hfrag + fused mh scores/exp (z-major: XCD = z%8)
    gemm32_kernel<1><<<dim3(Bb * Hh, Nn / 32, 1), 256, 0, stream>>>(
        x_bf, Ff, (long long)Nn * Ff, 3, WhF, 384LL * 512, 7,
        nullptr, 0, hfrag, 524288, Nn, nullptr, 1,
        a_heads, 7, E1p_mh, E1n_mh, E2pn_mh);
    // 2) multihead attention + elu -> x1_bf  (32-row tiles, XCD = bh%8)
    attn_v8_kernel<2048, 0, 1><<<dim3(Bb * Hh, Nn / 32, 1), 256, 0, stream>>>(
        hfrag, (const unsigned*)bits, E1p_mh, E1n_mh, E2pn_mh,
        x1_bf, Hh * Oo, nullptr, nullptr, 3);
    // 3) fused dual GEMM: h2frag (+sh scores) and lin
    gemm32_dual_kernel<<<dim3(Nn / 32, 2, Bb), 256, 0, stream>>>(
        x1_bf, Hh * Oo, (long long)Nn * Hh * Oo, WoF, h2frag, lin,
        a_out, E1p_sh, E1n_sh, E2pn_sh);
    // 4) single-head attention, 4-way j-split partials
    attn_v8_kernel<512, 1, 0><<<dim3(Nn / 32, Bb, 4), 256, 0, stream>>>(
        h2frag, (const unsigned*)bits, E1p_sh, E1n_sh, E2pn_sh,
        nullptr, 0, pacc, plsum, 0);
    // 5) final GEMM with fused combine -> d_out
    gemm32_final_kernel<<<dim3(Nn / 32, 1, Bb), 256, 0, stream>>>(
        pacc, plsum, lin, b_lin, WnF, b_ln, (float*)d_out);
}

// Round 19
// 261.768 us; speedup vs baseline: 1.1300x; 1.0088x over previous
//
#include <hip/hip_runtime.h>
#include <hip/hip_bf16.h>

constexpr int Bb = 2, Nn = 2048, Ff = 768, Hh = 8, Oo = 256;

typedef __attribute__((ext_vector_type(8)))  short   short8;
typedef __attribute__((ext_vector_type(16))) float   f32x16;
typedef __attribute__((ext_vector_type(4)))  unsigned short ushort4_t;

__device__ inline unsigned short f2bf(float f) {
    unsigned u = __float_as_uint(f);
    u = (u + 0x7FFFu + ((u >> 16) & 1u)) >> 16;   // RNE
    return (unsigned short)u;
}

// ======== B-fragment layout: frag id = nt32*(K/16)+kt, 1 KB each ========
__device__ inline void wfrag_kn_body(
        const float* __restrict__ W, unsigned short* __restrict__ out,
        int K, int N, int fblk, int t) {
    int f = fblk * 4 + (t >> 6);
    int slot = t & 63, kh = slot >> 5, lm = slot & 31;
    int nfk = K >> 4;
    int nt = f / nfk, kt = f - nt * nfk;
    const float* wp = W + (size_t)(kt * 16 + kh * 8) * N + nt * 32 + lm;
    ushort4_t o0, o1;
    o0.x = f2bf(wp[0]);             o0.y = f2bf(wp[(size_t)N]);
    o0.z = f2bf(wp[2 * (size_t)N]); o0.w = f2bf(wp[3 * (size_t)N]);
    o1.x = f2bf(wp[4 * (size_t)N]); o1.y = f2bf(wp[5 * (size_t)N]);
    o1.z = f2bf(wp[6 * (size_t)N]); o1.w = f2bf(wp[7 * (size_t)N]);
    unsigned short* op = out + (size_t)f * 512 + slot * 8;
    *(ushort4_t*)op = o0;
    *(ushort4_t*)(op + 4) = o1;
}

__device__ inline void wfrag_nk_body(
        const float* __restrict__ W, unsigned short* __restrict__ out,
        int K, int fblk, int t) {
    int f = fblk * 4 + (t >> 6);
    int slot = t & 63, kh = slot >> 5, lm = slot & 31;
    int nfk = K >> 4;
    int nt = f / nfk, kt = f - nt * nfk;
    const float* wp = W + (size_t)(nt * 32 + lm) * K + kt * 16 + kh * 8;
    float4 a = *(const float4*)wp, b = *(const float4*)(wp + 4);
    ushort4_t o0, o1;
    o0.x = f2bf(a.x); o0.y = f2bf(a.y); o0.z = f2bf(a.z); o0.w = f2bf(a.w);
    o1.x = f2bf(b.x); o1.y = f2bf(b.y); o1.z = f2bf(b.z); o1.w = f2bf(b.w);
    unsigned short* op = out + (size_t)f * 512 + slot * 8;
    *(ushort4_t*)op = o0;
    *(ushort4_t*)(op + 4) = o1;
}

// ---------------- merged prep: adjbits + x cast + all weight frag tables (1 launch) ----------------
__global__ __launch_bounds__(256) void prep_misc_kernel(
        const float* __restrict__ adj, unsigned long long* __restrict__ bits,
        const float* __restrict__ x, unsigned short* __restrict__ x_bf,
        const float* __restrict__ W_heads, unsigned short* __restrict__ WhF,
        const float* __restrict__ W_out,   unsigned short* __restrict__ WoF,
        const float* __restrict__ W_lin,   unsigned short* __restrict__ WlF,
        const float* __restrict__ W_ln,    unsigned short* __restrict__ WnF) {
    int blk = blockIdx.x, t = threadIdx.x;
    if (blk < 32768) {
        size_t gid = (size_t)blk * 256 + t;
        float v = adj[gid];
        unsigned long long m = __ballot(v > 0.f);
        if ((t & 63) == 0) bits[gid >> 6] = m;
    } else if (blk < 35840) {
        size_t i = (size_t)(blk - 32768) * 256 + t;
        float4 v = ((const float4*)x)[i];
        ushort4_t o;
        o.x = f2bf(v.x); o.y = f2bf(v.y); o.z = f2bf(v.z); o.w = f2bf(v.w);
        ((ushort4_t*)x_bf)[i] = o;
    } else if (blk < 36608) {
        int idx = blk - 35840;
        int head = idx / 96, fblk = idx - head * 96;
        wfrag_kn_body(W_heads + (size_t)head * Ff * Oo, WhF + (size_t)head * 384 * 512,
                      Ff, Oo, fblk, t);
    } else if (blk < 36864) {
        wfrag_kn_body(W_out, WoF, Hh * Oo, Oo, blk - 36608, t);
    } else if (blk < 37120) {
        wfrag_nk_body(W_lin, WlF, Hh * Oo, blk - 36864, t);
    } else {
        wfrag_nk_body(W_ln, WnF, Oo, blk - 37120, t);
    }
}

// ---------------- 32-row-tile MFMA GEMM, BK=128 (R18 verified) ----------------
template<int SWAPZ>
__global__ __launch_bounds__(256) void gemm32_kernel(
        const unsigned short* __restrict__ A, int K, long long sA, int bAshift,
        const unsigned short* __restrict__ BF, long long sB, int bmask,
        float* __restrict__ C, long long sC,
        unsigned short* __restrict__ CF, long long sCF, int Mtot,
        const float* __restrict__ bias, int mode,
        const float* __restrict__ aall, int amask,
        float* __restrict__ E1p, float* __restrict__ E1n, float2* __restrict__ E2pn) {
    int z  = SWAPZ ? blockIdx.x : blockIdx.z;
    int mx = SWAPZ ? blockIdx.y : blockIdx.x;
    A  += (size_t)(z >> bAshift) * sA;
    BF += (size_t)(z & bmask) * sB;
    if (C) C += (size_t)z * sC;
    if (CF) CF += (size_t)z * sCF;
    int m0 = mx * 32;
    int t = threadIdx.x;
    int wv = t >> 6, lane = t & 63;
    int lm = lane & 31, kh = lane >> 5;
    int nfk = K >> 4;
    __shared__ __align__(16) unsigned short As[32][136];
    f32x16 acc[2] = {};
    int sr = t >> 3, sc2 = (t & 7) * 16;
    const unsigned short* ag  = A + (size_t)(m0 + sr) * K + sc2;
    const unsigned short* bg0 = BF + (size_t)(wv * 2) * nfk * 512;
    const unsigned short* bg1 = bg0 + (size_t)nfk * 512;
    for (int k0 = 0; k0 < K; k0 += 128) {
        *(short8*)&As[sr][sc2]     = *(const short8*)(ag + k0);
        *(short8*)&As[sr][sc2 + 8] = *(const short8*)(ag + k0 + 8);
        int kt0 = k0 >> 4;
        __syncthreads();
#pragma unroll
        for (int s = 0; s < 8; ++s) {
            short8 a0 = *(const short8*)&As[lm][s * 16 + kh * 8];
            short8 b0 = *(const short8*)(bg0 + (size_t)(kt0 + s) * 512 + lane * 8);
            short8 b1 = *(const short8*)(bg1 + (size_t)(kt0 + s) * 512 + lane * 8);
            acc[0] = __builtin_amdgcn_mfma_f32_32x32x16_bf16(a0, b0, acc[0], 0, 0, 0);
            acc[1] = __builtin_amdgcn_mfma_f32_32x32x16_bf16(a0, b1, acc[1], 0, 0, 0);
        }
        __syncthreads();
    }
#pragma unroll
    for (int nt = 0; nt < 2; ++nt) {
        int colg = wv * 64 + nt * 32 + lm;
        float bv = (mode == 2) ? bias[colg] : 0.f;
        if (C) {
#pragma unroll
            for (int reg = 0; reg < 16; ++reg) {
                int rl = 4 * kh + (reg & 3) + 8 * (reg >> 2);
                float v = acc[nt][reg];
                if (mode == 2) { v += bv; v = fmaxf(v, 0.f); }
                C[(size_t)(m0 + rl) * 256 + colg] = v;
            }
        }
        if (mode == 1) {
#pragma unroll
            for (int q = 0; q < 4; ++q) {
                int kt = m0 / 16 + (q >> 1);
                size_t fi = ((size_t)(colg >> 5) * (Mtot / 16) + kt) * 512 +
                            ((q & 1) * 32 + (colg & 31)) * 8 + kh * 4;
                ushort4_t pk;
                pk.x = f2bf(acc[nt][q * 4 + 0]);
                pk.y = f2bf(acc[nt][q * 4 + 1]);
                pk.z = f2bf(acc[nt][q * 4 + 2]);
                pk.w = f2bf(acc[nt][q * 4 + 3]);
                *(ushort4_t*)(CF + fi) = pk;
            }
        }
    }
    if (aall) {
        const float* av = aall + (size_t)(z & amask) * 512;
        float a1v0 = av[wv * 64 + lm],       a1v1 = av[wv * 64 + 32 + lm];
        float a2v0 = av[256 + wv * 64 + lm], a2v1 = av[256 + wv * 64 + 32 + lm];
        float* sbuf = (float*)As;
#pragma unroll
        for (int reg = 0; reg < 16; ++reg) {
            int rl = 4 * kh + (reg & 3) + 8 * (reg >> 2);
            float v1 = acc[0][reg] * a1v0 + acc[1][reg] * a1v1;
            float v2 = acc[0][reg] * a2v0 + acc[1][reg] * a2v1;
#pragma unroll
            for (int m = 1; m <= 16; m <<= 1) {
                v1 += __shfl_xor(v1, m, 64);
                v2 += __shfl_xor(v2, m, 64);
            }
            if (lm == 0) { sbuf[rl * 8 + wv] = v1; sbuf[rl * 8 + 4 + wv] = v2; }
        }
        __syncthreads();
        if (t < 32) {
            float s1 = sbuf[t * 8] + sbuf[t * 8 + 1] + sbuf[t * 8 + 2] + sbuf[t * 8 + 3];
            float s2 = sbuf[t * 8 + 4] + sbuf[t * 8 + 5] + sbuf[t * 8 + 6] + sbuf[t * 8 + 7];
            size_t ei = (size_t)z * Nn + m0 + t;
            E1p[ei] = __expf(s1);
            E1n[ei] = __expf(0.2f * s1);
            E2pn[ei] = make_float2(__expf(s2), __expf(0.2f * s2));
        }
    }
}

// ---------------- 32-row dual GEMM, BK=128 (R18 verified) ----------------
__global__ __launch_bounds__(256) void gemm32_dual_kernel(
        const unsigned short* __restrict__ A, int K, long long sA,
        const unsigned short* __restrict__ BF,
        unsigned short* __restrict__ h2f, float* __restrict__ lin,
        const float* __restrict__ a_out,
        float* __restrict__ E1p, float* __restrict__ E1n, float2* __restrict__ E2pn) {
    int b = blockIdx.z, ng = blockIdx.y;
    A += (size_t)b * sA;
    int nfk = K >> 4;
    BF += (size_t)ng * 8 * nfk * 512;
    int m0 = blockIdx.x * 32;
    int t = threadIdx.x;
    int wv = t >> 6, lane = t & 63;
    int lm = lane & 31, kh = lane >> 5;
    __shared__ __align__(16) unsigned short As[32][136];
    f32x16 acc[2] = {};
    int sr = t >> 3, sc2 = (t & 7) * 16;
    const unsigned short* ag  = A + (size_t)(m0 + sr) * K + sc2;
    const unsigned short* bg0 = BF + (size_t)(wv * 2) * nfk * 512;
    const unsigned short* bg1 = bg0 + (size_t)nfk * 512;
    for (int k0 = 0; k0 < K; k0 += 128) {
        *(short8*)&As[sr][sc2]     = *(const short8*)(ag + k0);
        *(short8*)&As[sr][sc2 + 8] = *(const short8*)(ag + k0 + 8);
        int kt0 = k0 >> 4;
        __syncthreads();
#pragma unroll
        for (int s = 0; s < 8; ++s) {
            short8 a0 = *(const short8*)&As[lm][s * 16 + kh * 8];
            short8 b0 = *(const short8*)(bg0 + (size_t)(kt0 + s) * 512 + lane * 8);
            short8 b1 = *(const short8*)(bg1 + (size_t)(kt0 + s) * 512 + lane * 8);
            acc[0] = __builtin_amdgcn_mfma_f32_32x32x16_bf16(a0, b0, acc[0], 0, 0, 0);
            acc[1] = __builtin_amdgcn_mfma_f32_32x32x16_bf16(a0, b1, acc[1], 0, 0, 0);
        }
        __syncthreads();
    }
    if (ng == 1) {
        float* C = lin + (size_t)b * Nn * 256;
#pragma unroll
        for (int nt = 0; nt < 2; ++nt) {
            int colg = wv * 64 + nt * 32 + lm;
#pragma unroll
            for (int reg = 0; reg < 16; ++reg) {
                int rl = 4 * kh + (reg & 3) + 8 * (reg >> 2);
                C[(size_t)(m0 + rl) * 256 + colg] = acc[nt][reg];
            }
        }
    } else {
        unsigned short* CF = h2f + (size_t)b * 524288;
#pragma unroll
        for (int nt = 0; nt < 2; ++nt) {
            int colg = wv * 64 + nt * 32 + lm;
#pragma unroll
            for (int q = 0; q < 4; ++q) {
                int kt = m0 / 16 + (q >> 1);
                size_t fi = ((size_t)(colg >> 5) * 128 + kt) * 512 +
                            ((q & 1) * 32 + (colg & 31)) * 8 + kh * 4;
                ushort4_t pk;
                pk.x = f2bf(acc[nt][q * 4 + 0]);
                pk.y = f2bf(acc[nt][q * 4 + 1]);
                pk.z = f2bf(acc[nt][q * 4 + 2]);
                pk.w = f2bf(acc[nt][q * 4 + 3]);
                *(ushort4_t*)(CF + fi) = pk;
            }
        }
        float a1v0 = a_out[wv * 64 + lm],       a1v1 = a_out[wv * 64 + 32 + lm];
        float a2v0 = a_out[256 + wv * 64 + lm], a2v1 = a_out[256 + wv * 64 + 32 + lm];
        float* sbuf = (float*)As;
#pragma unroll
        for (int reg = 0; reg < 16; ++reg) {
            int rl = 4 * kh + (reg & 3) + 8 * (reg >> 2);
            float v1 = acc[0][reg] * a1v0 + acc[1][reg] * a1v1;
            float v2 = acc[0][reg] * a2v0 + acc[1][reg] * a2v1;
#pragma unroll
            for (int m = 1; m <= 16; m <<= 1) {
                v1 += __shfl_xor(v1, m, 64);
                v2 += __shfl_xor(v2, m, 64);
            }
            if (lm == 0) { sbuf[rl * 8 + wv] = v1; sbuf[rl * 8 + 4 + wv] = v2; }
        }
        __syncthreads();
        if (t < 32) {
            float s1 = sbuf[t * 8] + sbuf[t * 8 + 1] + sbuf[t * 8 + 2] + sbuf[t * 8 + 3];
            float s2 = sbuf[t * 8 + 4] + sbuf[t * 8 + 5] + sbuf[t * 8 + 6] + sbuf[t * 8 + 7];
            size_t ei = (size_t)b * Nn + m0 + t;
            E1p[ei] = __expf(s1);
            E1n[ei] = __expf(0.2f * s1);
            E2pn[ei] = make_float2(__expf(s2), __expf(0.2f * s2));
        }
    }
}

// ---------------- final GEMM with fused combine, BK=128 ----------------
__global__ __launch_bounds__(256) void gemm32_final_kernel(
        const float* __restrict__ pacc, const float* __restrict__ plsum,
        const float* __restrict__ lin, const float* __restrict__ b_lin,
        const unsigned short* __restrict__ BF, const float* __restrict__ b_ln,
        float* __restrict__ out) {
    int b = blockIdx.z;
    int m0 = blockIdx.x * 32;
    int t = threadIdx.x;
    int wv = t >> 6, lane = t & 63;
    int lm = lane & 31, kh = lane >> 5;
    constexpr int nfk = 16;   // K = 256
    __shared__ __align__(16) unsigned short As[32][136];
    f32x16 acc[2] = {};
    int sr = t >> 3, sc2 = (t & 7) * 16;
    int row = m0 + sr;
    int BN = Bb * Nn;
    size_t prow = (size_t)b * Nn + row;
    float li = 1.f / (plsum[prow] + plsum[prow + BN] + plsum[prow + 2 * BN] + plsum[prow + 3 * BN]);
    size_t ps4 = (size_t)Bb * Nn * 256;
    const unsigned short* bg0 = BF + (size_t)(wv * 2) * nfk * 512;
    const unsigned short* bg1 = bg0 + (size_t)nfk * 512;
    for (int k0 = 0; k0 < 256; k0 += 128) {
        int o = k0 + sc2;
        size_t pidx = prow * 256 + o;
#pragma unroll
        for (int g = 0; g < 4; ++g) {
            float4 s4 = *(const float4*)(pacc + pidx + 4 * g);
#pragma unroll
            for (int k = 1; k < 4; ++k) {
                float4 q = *(const float4*)(pacc + k * ps4 + pidx + 4 * g);
                s4.x += q.x; s4.y += q.y; s4.z += q.z; s4.w += q.w;
            }
            float4 lv = *(const float4*)(lin + pidx + 4 * g);
            float4 bv = *(const float4*)(b_lin + o + 4 * g);
            ushort4_t pk;
            pk.x = f2bf(s4.x * li + lv.x + bv.x);
            pk.y = f2bf(s4.y * li + lv.y + bv.y);
            pk.z = f2bf(s4.z * li + lv.z + bv.z);
            pk.w = f2bf(s4.w * li + lv.w + bv.w);
            *(ushort4_t*)&As[sr][sc2 + 4 * g] = pk;
        }
        int kt0 = k0 >> 4;
        __syncthreads();
#pragma unroll
        for (int s = 0; s < 8; ++s) {
            short8 a0 = *(const short8*)&As[lm][s * 16 + kh * 8];
            short8 b0 = *(const short8*)(bg0 + (size_t)(kt0 + s) * 512 + lane * 8);
            short8 b1 = *(const short8*)(bg1 + (size_t)(kt0 + s) * 512 + lane * 8);
            acc[0] = __builtin_amdgcn_mfma_f32_32x32x16_bf16(a0, b0, acc[0], 0, 0, 0);
            acc[1] = __builtin_amdgcn_mfma_f32_32x32x16_bf16(a0, b1, acc[1], 0, 0, 0);
        }
        __syncthreads();
    }
    float* C = out + (size_t)b * Nn * 256;
#pragma unroll
    for (int nt = 0; nt < 2; ++nt) {
        int colg = wv * 64 + nt * 32 + lm;
        float bv = b_ln[colg];
#pragma unroll
        for (int reg = 0; reg < 16; ++reg) {
            int rl = 4 * kh + (reg & 3) + 8 * (reg >> 2);
            float v = fmaxf(acc[nt][reg] + bv, 0.f);
            C[(size_t)(m0 + rl) * 256 + colg] = v;
        }
    }
}

// ---------------- attention v8: 32 i-rows/block, frag B (R15-R18 verified) ----------------
template<int JLEN, int MODE, int SWAPXY>
__global__ __launch_bounds__(256, 4) void attn_v8_kernel(
        const unsigned short* __restrict__ hfrag,
        const unsigned* __restrict__ bits,
        const float* __restrict__ E1p, const float* __restrict__ E1n,
        const float2* __restrict__ E2pn,
        unsigned short* __restrict__ outbf, int ldo,
        float* __restrict__ pacc, float* __restrict__ plsum,
        int hshift) {
    constexpr int W = JLEN / 32, NC = JLEN / 64, ABS = W + 1;
    int it = SWAPXY ? blockIdx.y : blockIdx.x;
    int bh = SWAPXY ? blockIdx.x : blockIdx.y;
    int js = blockIdx.z;
    int b = bh >> hshift, hd = bh & ((1 << hshift) - 1);
    int i0 = it * 32, jbase = js * JLEN;
    int kt0 = js * (JLEN / 16);
    int t = threadIdx.x, lane = t & 63;
    int wv = t >> 6, lm = lane & 31, kh = lane >> 5;
    int ti = t & 31, jq = t >> 5;

    __shared__ unsigned ab[32 * ABS];
    __shared__ __align__(16) unsigned short ps[2][32][64];
    __shared__ float lred[32][9];
    __shared__ float linv[32];

    const unsigned* bb = bits + ((size_t)b * Nn + i0) * 64 + (jbase >> 5);
    for (int k = t; k < 32 * W; k += 256) {
        int r = k / W, w0 = k - r * W;
        ab[r * ABS + w0] = bb[(size_t)r * 64 + w0];
    }
    __syncthreads();   // ab[] must be visible before computeP

    float e1p = E1p[(size_t)bh * Nn + i0 + ti];
    float e1n = E1n[(size_t)bh * Nn + i0 + ti];
    const float4* e2base = (const float4*)(E2pn + (size_t)bh * Nn + jbase);

    const unsigned short* bg0 = hfrag + (size_t)bh * 524288 + (size_t)(wv * 2) * 128 * 512;
    const unsigned short* bg1 = bg0 + 128 * 512;

    f32x16 acc[2] = {};
    float lp0 = 0.f, lp1 = 0.f;
    short8 Bpp[2][2];

    auto loadBs = [&](int c, int s, int slot) {
        int kt = kt0 + c * 4 + s;
        Bpp[slot][0] = *(const short8*)(bg0 + (size_t)kt * 512 + lane * 8);
        Bpp[slot][1] = *(const short8*)(bg1 + (size_t)kt * 512 + lane * 8);
    };
    auto computeP = [&](int c, int buf) {
        int cj = c * 64;
        unsigned word = ab[ti * ABS + (cj >> 5) + (jq >> 2)];
        unsigned field = (word >> ((jq & 3) * 8)) & 0xffu;
        const float4* ep = e2base + ((cj + jq * 8) >> 1);
        unsigned pk[4];
#pragma unroll
        for (int u = 0; u < 4; ++u) {
            float4 q = ep[u];
            float p0 = fmaxf(e1p * q.x, e1n * q.y);   // select==max (exact)
            p0 = ((field >> (2 * u)) & 1u) ? p0 : 0.f;
            float p1 = fmaxf(e1p * q.z, e1n * q.w);
            p1 = ((field >> (2 * u + 1)) & 1u) ? p1 : 0.f;
            if (u & 1) lp1 += p0 + p1; else lp0 += p0 + p1;
            __hip_bfloat162 hv = __float22bfloat162_rn(make_float2(p0, p1));
            pk[u] = *(unsigned*)&hv;
        }
        uint4 v; v.x = pk[0]; v.y = pk[1]; v.z = pk[2]; v.w = pk[3];
        *(uint4*)&ps[buf][ti][(jq ^ (ti & 7)) * 8] = v;
    };
    auto mfmaS = [&](int buf, int s, int slot) {
        int g = 2 * s + kh;
        short8 a0 = *(const short8*)&ps[buf][lm][(g ^ (lm & 7)) * 8];
        acc[0] = __builtin_amdgcn_mfma_f32_32x32x16_bf16(a0, Bpp[slot][0], acc[0], 0, 0, 0);
        acc[1] = __builtin_amdgcn_mfma_f32_32x32x16_bf16(a0, Bpp[slot][1], acc[1], 0, 0, 0);
    };

    computeP(0, 0);
    loadBs(0, 0, 0);
    __syncthreads();
    for (int c = 0; c < NC; ++c) {
        int cb = c & 1, nb = cb ^ 1;
        if (c + 1 < NC) computeP(c + 1, nb);
        loadBs(c, 1, 1);            mfmaS(cb, 0, 0);
        loadBs(c, 2, 0);            mfmaS(cb, 1, 1);
        loadBs(c, 3, 1);            mfmaS(cb, 2, 0);
        if (c + 1 < NC) loadBs(c + 1, 0, 0);
        mfmaS(cb, 3, 1);
        __syncthreads();
    }

    lred[ti][jq] = lp0 + lp1;
    __syncthreads();
    if (MODE == 0) {
        if (t < 32) {
            float s = 0.f;
#pragma unroll
            for (int k = 0; k < 8; ++k) s += lred[t][k];
            linv[t] = 1.f / s;
        }
        __syncthreads();
#pragma unroll
        for (int nt = 0; nt < 2; ++nt) {
            int o = wv * 64 + nt * 32 + lm;
#pragma unroll
            for (int reg = 0; reg < 16; ++reg) {
                int rl = 4 * kh + (reg & 3) + 8 * (reg >> 2);
                float v = acc[nt][reg] * linv[rl];
                v = v > 0.f ? v : expm1f(v);   // elu (layer 1)
                outbf[((size_t)b * Nn + i0 + rl) * ldo + (size_t)hd * Oo + o] = f2bf(v);
            }
        }
    } else {
        if (t < 32) {
            float s = 0.f;
#pragma unroll
            for (int k = 0; k < 8; ++k) s += lred[t][k];
            plsum[((size_t)js * Bb + b) * Nn + i0 + t] = s;
        }
        float* pa = pacc + (((size_t)js * Bb + b) * Nn) * 256;
#pragma unroll
        for (int nt = 0; nt < 2; ++nt) {
            int o = wv * 64 + nt * 32 + lm;
#pragma unroll
            for (int reg = 0; reg < 16; ++reg) {
                int rl = 4 * kh + (reg & 3) + 8 * (reg >> 2);
                pa[(size_t)(i0 + rl) * 256 + o] = acc[nt][reg];
            }
        }
    }
}

extern "C" void kernel_launch(void* const* d_in, const int* in_sizes, int n_in,
                              void* d_out, int out_size, void* d_ws, size_t ws_size,
                              hipStream_t stream) {
    const float* x       = (const float*)d_in[0];
    const float* adj     = (const float*)d_in[1];
    const float* W_heads = (const float*)d_in[3];
    const float* a_heads = (const float*)d_in[4];
    const float* W_out   = (const float*)d_in[5];
    const float* a_out   = (const float*)d_in[6];
    const float* W_lin   = (const float*)d_in[7];
    const float* b_lin   = (const float*)d_in[8];
    const float* W_ln    = (const float*)d_in[9];
    const float* b_ln    = (const float*)d_in[10];

    char* w = (char*)d_ws;
    float* pacc     = (float*)(w);                    // 4x4 MB (sh partials)
    float* lin      = (float*)(w + 33554432);
    float* E1p_mh   = (float*)(w + 41943040);
    float* E1n_mh   = (float*)(w + 42074112);
    float2* E2pn_mh = (float2*)(w + 42205184);
    float* E1p_sh   = (float*)(w + 42467328);
    float* E1n_sh   = (float*)(w + 42483712);
    float2* E2pn_sh = (float2*)(w + 42500096);
    unsigned long long* bits = (unsigned long long*)(w + 42532864);
    unsigned short* x_bf  = (unsigned short*)(w + 43581440);
    unsigned short* WhF   = (unsigned short*)(w + 49872896);
    unsigned short* WoF   = (unsigned short*)(w + 53018624);
    unsigned short* WlF   = (unsigned short*)(w + 54067200);
    unsigned short* WnF   = (unsigned short*)(w + 55115776);
    unsigned short* hfrag = (unsigned short*)(w + 55246848);   // 16 MB
    unsigned short* h2frag= (unsigned short*)(w + 72024064);   // 2 MB
    unsigned short* x1_bf = (unsigned short*)(w + 74121216);
    float* plsum = E1p_mh;

    // 0) merged prep: adjbits + x cast + all weight frags (1 launch)
    prep_misc_kernel<<<37152, 256, 0, stream>>>(
        adj, bits, x, x_bf, W_heads, WhF, W_out, WoF, W_lin, WlF, W_ln, WnF);

    // 1) h = x @ W_heads -> hfrag + fused mh scores/exp (z-major: XCD = z%8)
    gemm32_kernel<1><<<dim3(Bb * Hh, Nn / 32, 1), 256, 0, stream>>>(
        x_bf, Ff, (long long)Nn * Ff, 3, WhF, 384LL * 512, 7,
        nullptr, 0, hfrag, 524288, Nn, nullptr, 1,
        a_heads, 7, E1p_mh, E1n_mh, E2pn_mh);
    // 2) multihead attention + elu -> x1_bf  (32-row tiles, XCD = bh%8)
    attn_v8_kernel<2048, 0, 1><<<dim3(Bb * Hh, Nn / 32, 1), 256, 0, stream>>>(
        hfrag, (const unsigned*)bits, E1p_mh, E1n_mh, E2pn_mh,
        x1_bf, Hh * Oo, nullptr, nullptr, 3);
    // 3) fused dual GEMM: h2frag (+sh scores) and lin
    gemm32_dual_kernel<<<dim3(Nn / 32, 2, Bb), 256, 0, stream>>>(
        x1_bf, Hh * Oo, (long long)Nn * Hh * Oo, WoF, h2frag, lin,
        a_out, E1p_sh, E1n_sh, E2pn_sh);
    // 4) single-head attention, 4-way j-split partials
    attn_v8_kernel<512, 1, 0><<<dim3(Nn / 32, Bb, 4), 256, 0, stream>>>(
        h2frag, (const unsigned*)bits, E1p_sh, E1n_sh, E2pn_sh,
        nullptr, 0, pacc, plsum, 0);
    // 5) final GEMM with fused combine -> d_out
    gemm32_final_kernel<<<dim3(Nn / 32, 1, Bb), 256, 0, stream>>>(
        pacc, plsum, lin, b_lin, WnF, b_ln, (float*)d_out);
}